// Round 18
// baseline (441.725 us; speedup 1.0000x reference)
//
#include <hip/hip_runtime.h>
#include <hip/hip_bf16.h>
#include <math.h>

#define B_ 2
#define S_ 1024
#define H_ 1024
#define NH_ 16
#define NKV_ 4
#define HD_ 64
#define E_ 8
#define I_ 3584
#define T_ (B_*S_)

#define BM 64
#define BN 64
#define MBM 128   // gateup M-tile
#define DBM 64    // down / dense M-tile
#define MBK 64    // dense K-step
#define KST 32    // MoE K-step (m97 geometry)

typedef __bf16 bf16x8 __attribute__((ext_vector_type(8)));
typedef float f32x4 __attribute__((ext_vector_type(4)));

__device__ __forceinline__ __bf16 bf_hi(float f) { return (__bf16)f; }
__device__ __forceinline__ __bf16 bf_lo(float f, __bf16 h) { return (__bf16)(f - (float)h); }

// XOR swizzle for [rows][64 bf16] tiles (128 B row stride). (dense GEMM only)
__device__ __forceinline__ int swz128(int row, int col) {
    return (row * 128 + col * 2) ^ ((row & 7) << 4);
}

// async global->LDS, 16B per lane; LDS dest = uniform base + lane*16 (HW).
__device__ __forceinline__ void gload16(const __bf16* g, __bf16* l) {
    __builtin_amdgcn_global_load_lds(
        (const __attribute__((address_space(1))) void*)g,
        (__attribute__((address_space(3))) void*)l, 16, 0, 0);
}

// ---------------- fp32 -> (hi,lo) bf16 planes, optional scale ----------------
__global__ __launch_bounds__(256) void split_bf16_kernel(
    const float* __restrict__ src, __bf16* __restrict__ hi, __bf16* __restrict__ lo,
    float scale, int n8)
{
    int idx = blockIdx.x * 256 + threadIdx.x;
    if (idx >= n8) return;
    const float4* s = (const float4*)src + (size_t)idx * 2;
    float4 a = s[0], b = s[1];
    float f[8] = {a.x, a.y, a.z, a.w, b.x, b.y, b.z, b.w};
    bf16x8 vh, vl;
#pragma unroll
    for (int i = 0; i < 8; i++) {
        float x = f[i] * scale;
        __bf16 h = bf_hi(x);
        vh[i] = h;
        vl[i] = bf_lo(x, h);
    }
    ((bf16x8*)hi)[idx] = vh;
    ((bf16x8*)lo)[idx] = vl;
}

// ---------------- fp32 [M][N] -> bf16 transposed [N][M], per expert/z-slice ----------------
__global__ __launch_bounds__(256) void transpose_cvt_kernel(
    const float* __restrict__ src, __bf16* __restrict__ dst, int M, int N)
{
    int e = blockIdx.z;
    src += (size_t)e * M * N;
    dst += (size_t)e * M * N;
    int n0 = blockIdx.x * 64, m0 = blockIdx.y * 64;
    __shared__ __bf16 Ts[64][72];
    int tid = threadIdx.x;
#pragma unroll
    for (int i = 0; i < 16; i++) {
        int row = i * 4 + (tid >> 6);
        int col = tid & 63;
        Ts[row][col] = (__bf16)src[(size_t)(m0 + row) * N + n0 + col];
    }
    __syncthreads();
#pragma unroll
    for (int j = 0; j < 2; j++) {
        int n = (tid >> 3) + j * 32;
        int k8 = (tid & 7) * 8;
        bf16x8 v;
#pragma unroll
        for (int ii = 0; ii < 8; ii++) v[ii] = Ts[k8 + ii][n];
        *(bf16x8*)(dst + (size_t)(n0 + n) * M + m0 + k8) = v;
    }
}

// ---------------- RMSNorm: bf16 out (+ optional fp32 out) ----------------
__global__ __launch_bounds__(256) void rmsnorm_kernel(
    const float* __restrict__ x, const float* __restrict__ w,
    __bf16* __restrict__ outb, float* __restrict__ outf)
{
    int row = blockIdx.x;
    int tid = threadIdx.x;
    const float* xr = x + (size_t)row * H_;
    float vals[4];
    float ss = 0.f;
#pragma unroll
    for (int i = 0; i < 4; i++) {
        vals[i] = xr[tid + 256 * i];
        ss += vals[i] * vals[i];
    }
#pragma unroll
    for (int off = 32; off; off >>= 1) ss += __shfl_xor(ss, off);
    __shared__ float red[4];
    int wid = tid >> 6;
    if ((tid & 63) == 0) red[wid] = ss;
    __syncthreads();
    float tot = red[0] + red[1] + red[2] + red[3];
    float scale = rsqrtf(tot * (1.0f / H_) + 1e-5f);
#pragma unroll
    for (int i = 0; i < 4; i++) {
        float y = vals[i] * scale * w[tid + 256 * i];
        outb[(size_t)row * H_ + tid + 256 * i] = (__bf16)y;
        if (outf) outf[(size_t)row * H_ + tid + 256 * i] = y;
    }
}

// ---------------- Dense bf16 GEMM: A[M][K] bf16, BT[N][K] bf16 -> C[M][N] f32 (+res) ----
__global__ __launch_bounds__(256) void gemm_bf16bt(
    const __bf16* __restrict__ A, const __bf16* __restrict__ BT,
    float* __restrict__ C, const float* __restrict__ res,
    int M, int N, int Kd)
{
    int m0 = blockIdx.y * DBM;
    int n0 = blockIdx.x * BN;
    __shared__ __bf16 As[2][DBM * MBK];
    __shared__ __bf16 Bs[2][BN * MBK];
    int tid = threadIdx.x;
    int lane = tid & 63, wid = tid >> 6;
    f32x4 acc[4] = {};
    int ar = tid >> 2, ac = (tid & 3) * 16;
    int bn = tid >> 2, bc = (tid & 3) * 16;
    const __bf16* abase = A + (size_t)(m0 + ar) * Kd + ac;
    const __bf16* bbase = BT + (size_t)(n0 + bn) * Kd + bc;
    {
        char* Asb = (char*)As[0];
        char* Bsb = (char*)Bs[0];
#pragma unroll
        for (int g = 0; g < 2; g++) {
            *(bf16x8*)(Asb + swz128(ar, ac + g * 8)) = *(const bf16x8*)(abase + g * 8);
            *(bf16x8*)(Bsb + swz128(bn, bc + g * 8)) = *(const bf16x8*)(bbase + g * 8);
        }
    }
    bf16x8 pa[2], pb[2];
    if (Kd > MBK) {
#pragma unroll
        for (int g = 0; g < 2; g++) {
            pa[g] = *(const bf16x8*)(abase + MBK + g * 8);
            pb[g] = *(const bf16x8*)(bbase + MBK + g * 8);
        }
    }
    int cur = 0;
    int r = lane & 15, q8 = (lane >> 4) * 8;
    for (int kt = 0; kt < Kd; kt += MBK) {
        __syncthreads();
        char* Asb = (char*)As[cur];
        char* Bsb = (char*)Bs[cur];
#pragma unroll
        for (int kk = 0; kk < 2; kk++) {
            bf16x8 af = *(const bf16x8*)(Asb + swz128(wid * 16 + r, kk * 32 + q8));
            bf16x8 bfr[4];
#pragma unroll
            for (int n = 0; n < 4; n++)
                bfr[n] = *(const bf16x8*)(Bsb + swz128(n * 16 + r, kk * 32 + q8));
#pragma unroll
            for (int n = 0; n < 4; n++)
                acc[n] = __builtin_amdgcn_mfma_f32_16x16x32_bf16(af, bfr[n], acc[n], 0, 0, 0);
        }
        int kn = kt + MBK;
        if (kn < Kd) {
            char* Asw = (char*)As[cur ^ 1];
            char* Bsw = (char*)Bs[cur ^ 1];
#pragma unroll
            for (int g = 0; g < 2; g++) {
                *(bf16x8*)(Asw + swz128(ar, ac + g * 8)) = pa[g];
                *(bf16x8*)(Bsw + swz128(bn, bc + g * 8)) = pb[g];
            }
            int k2 = kn + MBK;
            if (k2 < Kd) {
#pragma unroll
                for (int g = 0; g < 2; g++) {
                    pa[g] = *(const bf16x8*)(abase + k2 + g * 8);
                    pb[g] = *(const bf16x8*)(bbase + k2 + g * 8);
                }
            }
            cur ^= 1;
        }
    }
    int cl = lane & 15, rb = (lane >> 4) * 4;
#pragma unroll
    for (int n = 0; n < 4; n++)
#pragma unroll
        for (int j = 0; j < 4; j++) {
            int row = m0 + wid * 16 + rb + j;
            int col = n0 + n * 16 + cl;
            size_t o = (size_t)row * N + col;
            float v = acc[n][j];
            if (res) v += res[o];
            C[o] = v;
        }
}

// ---------------- RoPE + hi/lo split ----------------
__global__ void rope_split_kernel(
    const float* __restrict__ x, __bf16* __restrict__ hi, __bf16* __restrict__ lo,
    float scale, int heads, int total)
{
    int idx = blockIdx.x * blockDim.x + threadIdx.x;
    if (idx >= total) return;
    int j = idx & 31;
    int th = idx >> 5;
    int h = th % heads;
    int t = th / heads;
    int s = t & (S_ - 1);
    float inv = powf(1e6f, -(float)j / 32.0f);
    float ang = (float)s * inv;
    float c = cosf(ang), sn = sinf(ang);
    size_t base = (size_t)t * heads * HD_ + (size_t)h * HD_;
    float x1 = x[base + j], x2 = x[base + 32 + j];
    float y1 = (x1 * c - x2 * sn) * scale;
    float y2 = (x2 * c + x1 * sn) * scale;
    __bf16 h1 = bf_hi(y1), h2 = bf_hi(y2);
    hi[base + j] = h1;       lo[base + j] = bf_lo(y1, h1);
    hi[base + 32 + j] = h2;  lo[base + 32 + j] = bf_lo(y2, h2);
}

// ---------------- MFMA flash attention — hi/lo planes, bf16 attn out ----------------
#define LP 72
__global__ __launch_bounds__(256) void flash_kernel(
    const __bf16* __restrict__ qhi, const __bf16* __restrict__ qlo_g,
    const __bf16* __restrict__ khi, const __bf16* __restrict__ klo,
    const __bf16* __restrict__ vhi, const __bf16* __restrict__ vlo,
    __bf16* __restrict__ o)
{
    __shared__ __bf16 Ks [64][LP];
    __shared__ __bf16 Ksl[64][LP];
    __shared__ __bf16 Vt [64][LP];
    __shared__ __bf16 Vtl[64][LP];
    __shared__ __bf16 Pl [4][16][LP];
    __shared__ __bf16 Pll[4][16][LP];

    int tid = threadIdx.x;
    int lane = tid & 63, wid = tid >> 6;
    int qr = lane & 15, quad = lane >> 4;
    int qt = (S_ / 16 - 1) - blockIdx.x;
    int kvh = blockIdx.y, b = blockIdx.z;
    int h = kvh * 4 + wid;
    int s0 = qt * 16;

    size_t qoff = ((size_t)(b * S_ + s0 + qr) * NH_ + h) * HD_ + quad * 8;
    bf16x8 qf[2], qlo[2];
#pragma unroll
    for (int ks = 0; ks < 2; ks++) {
        qf[ks]  = *(const bf16x8*)(qhi  + qoff + ks * 32);
        qlo[ks] = *(const bf16x8*)(qlo_g + qoff + ks * 32);
    }

    float m_run[4], l_run[4];
    f32x4 o_acc[4] = {};
#pragma unroll
    for (int j = 0; j < 4; j++) { m_run[j] = -1e30f; l_run[j] = 0.f; }

    int skey = tid >> 2, shd0 = (tid & 3) * 16;
    int vhd = tid & 63, vkey0 = (tid >> 6) * 16;

    for (int kt = 0; kt <= s0 + 15; kt += 64) {
        __syncthreads();
        {
            size_t koff = ((size_t)(b * S_ + kt + skey) * NKV_ + kvh) * HD_ + shd0;
            *(bf16x8*)&Ks [skey][shd0]     = *(const bf16x8*)(khi + koff);
            *(bf16x8*)&Ks [skey][shd0 + 8] = *(const bf16x8*)(khi + koff + 8);
            *(bf16x8*)&Ksl[skey][shd0]     = *(const bf16x8*)(klo + koff);
            *(bf16x8*)&Ksl[skey][shd0 + 8] = *(const bf16x8*)(klo + koff + 8);
        }
        {
            const __bf16* vh = vhi + ((size_t)(b * S_ + kt + vkey0) * NKV_ + kvh) * HD_ + vhd;
            const __bf16* vl = vlo + ((size_t)(b * S_ + kt + vkey0) * NKV_ + kvh) * HD_ + vhd;
            bf16x8 th0, th1, tl0, tl1;
#pragma unroll
            for (int i = 0; i < 8; i++) {
                th0[i] = vh[(size_t)i * (NKV_ * HD_)];
                th1[i] = vh[(size_t)(i + 8) * (NKV_ * HD_)];
                tl0[i] = vl[(size_t)i * (NKV_ * HD_)];
                tl1[i] = vl[(size_t)(i + 8) * (NKV_ * HD_)];
            }
            *(bf16x8*)&Vt [vhd][vkey0]     = th0;
            *(bf16x8*)&Vt [vhd][vkey0 + 8] = th1;
            *(bf16x8*)&Vtl[vhd][vkey0]     = tl0;
            *(bf16x8*)&Vtl[vhd][vkey0 + 8] = tl1;
        }
        __syncthreads();

        f32x4 sc4[4];
#pragma unroll
        for (int sub = 0; sub < 4; sub++) {
            int krow = sub * 16 + qr;
            bf16x8 kh0 = *(const bf16x8*)&Ks [krow][quad * 8];
            bf16x8 kh1 = *(const bf16x8*)&Ks [krow][32 + quad * 8];
            bf16x8 kl0 = *(const bf16x8*)&Ksl[krow][quad * 8];
            bf16x8 kl1 = *(const bf16x8*)&Ksl[krow][32 + quad * 8];
            f32x4 z = {};
            z = __builtin_amdgcn_mfma_f32_16x16x32_bf16(qf[0],  kh0, z, 0, 0, 0);
            z = __builtin_amdgcn_mfma_f32_16x16x32_bf16(qf[1],  kh1, z, 0, 0, 0);
            z = __builtin_amdgcn_mfma_f32_16x16x32_bf16(qlo[0], kh0, z, 0, 0, 0);
            z = __builtin_amdgcn_mfma_f32_16x16x32_bf16(qlo[1], kh1, z, 0, 0, 0);
            z = __builtin_amdgcn_mfma_f32_16x16x32_bf16(qf[0],  kl0, z, 0, 0, 0);
            z = __builtin_amdgcn_mfma_f32_16x16x32_bf16(qf[1],  kl1, z, 0, 0, 0);
            sc4[sub] = z;
        }
        if (kt + 63 > s0) {
#pragma unroll
            for (int sub = 0; sub < 4; sub++)
#pragma unroll
                for (int j = 0; j < 4; j++) {
                    int key = kt + sub * 16 + qr;
                    int row = s0 + quad * 4 + j;
                    if (key > row) sc4[sub][j] = -1e30f;
                }
        }
#pragma unroll
        for (int j = 0; j < 4; j++) {
            float mx = fmaxf(fmaxf(sc4[0][j], sc4[1][j]), fmaxf(sc4[2][j], sc4[3][j]));
#pragma unroll
            for (int off = 1; off < 16; off <<= 1) mx = fmaxf(mx, __shfl_xor(mx, off));
            float mn = fmaxf(m_run[j], mx);
            float scale = __expf(m_run[j] - mn);
            m_run[j] = mn;
            float rs = 0.f;
#pragma unroll
            for (int sub = 0; sub < 4; sub++) {
                float pe = __expf(sc4[sub][j] - mn);
                sc4[sub][j] = pe;
                rs += pe;
            }
#pragma unroll
            for (int off = 1; off < 16; off <<= 1) rs += __shfl_xor(rs, off);
            l_run[j] = l_run[j] * scale + rs;
#pragma unroll
            for (int sub = 0; sub < 4; sub++) o_acc[sub][j] *= scale;
        }
#pragma unroll
        for (int sub = 0; sub < 4; sub++)
#pragma unroll
            for (int j = 0; j < 4; j++) {
                float pe = sc4[sub][j];
                __bf16 hh = bf_hi(pe);
                Pl [wid][quad * 4 + j][sub * 16 + qr] = hh;
                Pll[wid][quad * 4 + j][sub * 16 + qr] = bf_lo(pe, hh);
            }
        __syncthreads();
        bf16x8 ph0 = *(const bf16x8*)&Pl [wid][qr][quad * 8];
        bf16x8 ph1 = *(const bf16x8*)&Pl [wid][qr][32 + quad * 8];
        bf16x8 pl0 = *(const bf16x8*)&Pll[wid][qr][quad * 8];
        bf16x8 pl1 = *(const bf16x8*)&Pll[wid][qr][32 + quad * 8];
#pragma unroll
        for (int sub = 0; sub < 4; sub++) {
            int vrow = sub * 16 + qr;
            bf16x8 vh0 = *(const bf16x8*)&Vt [vrow][quad * 8];
            bf16x8 vh1 = *(const bf16x8*)&Vt [vrow][32 + quad * 8];
            bf16x8 vl0 = *(const bf16x8*)&Vtl[vrow][quad * 8];
            bf16x8 vl1 = *(const bf16x8*)&Vtl[vrow][32 + quad * 8];
            o_acc[sub] = __builtin_amdgcn_mfma_f32_16x16x32_bf16(ph0, vh0, o_acc[sub], 0, 0, 0);
            o_acc[sub] = __builtin_amdgcn_mfma_f32_16x16x32_bf16(ph1, vh1, o_acc[sub], 0, 0, 0);
            o_acc[sub] = __builtin_amdgcn_mfma_f32_16x16x32_bf16(ph0, vl0, o_acc[sub], 0, 0, 0);
            o_acc[sub] = __builtin_amdgcn_mfma_f32_16x16x32_bf16(ph1, vl1, o_acc[sub], 0, 0, 0);
            o_acc[sub] = __builtin_amdgcn_mfma_f32_16x16x32_bf16(pl0, vh0, o_acc[sub], 0, 0, 0);
            o_acc[sub] = __builtin_amdgcn_mfma_f32_16x16x32_bf16(pl1, vh1, o_acc[sub], 0, 0, 0);
        }
    }
#pragma unroll
    for (int j = 0; j < 4; j++) {
        float inv = 1.f / l_run[j];
        int row = s0 + quad * 4 + j;
#pragma unroll
        for (int sub = 0; sub < 4; sub++)
            o[((size_t)(b * S_ + row) * NH_ + h) * HD_ + sub * 16 + qr] = (__bf16)(o_acc[sub][j] * inv);
    }
}

// ---------------- Router ----------------
__global__ __launch_bounds__(256) void router_kernel(
    const float* __restrict__ xn, const float* __restrict__ rw,
    int* __restrict__ top_i, float* __restrict__ top_w)
{
    int wid = threadIdx.x >> 6, lane = threadIdx.x & 63;
    int t = blockIdx.x * 4 + wid;
    const float* xr = xn + (size_t)t * H_;
    float acc[E_] = {};
    for (int c = 0; c < H_ / 64; c++) {
        float xd = xr[c * 64 + lane];
        const float* wrow = rw + (size_t)(c * 64 + lane) * E_;
#pragma unroll
        for (int e = 0; e < E_; e++) acc[e] += xd * wrow[e];
    }
#pragma unroll
    for (int e = 0; e < E_; e++) {
        float r = acc[e];
#pragma unroll
        for (int off = 32; off; off >>= 1) r += __shfl_xor(r, off);
        acc[e] = r;
    }
    if (lane == 0) {
        float mx = acc[0];
        for (int e = 1; e < E_; e++) mx = fmaxf(mx, acc[e]);
        float p[E_], sum = 0.f;
        for (int e = 0; e < E_; e++) { p[e] = __expf(acc[e] - mx); sum += p[e]; }
        float inv_s = 1.f / sum;
        for (int e = 0; e < E_; e++) p[e] *= inv_s;
        int i0 = 0;
        for (int e = 1; e < E_; e++) if (p[e] > p[i0]) i0 = e;
        int i1 = (i0 == 0) ? 1 : 0;
        for (int e = 0; e < E_; e++) if (e != i0 && p[e] > p[i1]) i1 = e;
        float v0 = p[i0], v1 = p[i1], inv = 1.f / (v0 + v1);
        top_i[t * 2] = i0; top_i[t * 2 + 1] = i1;
        top_w[t * 2] = v0 * inv; top_w[t * 2 + 1] = v1 * inv;
    }
}

// ---------------- Assignment ----------------
__global__ void assign_kernel(
    const int* __restrict__ top_i, const float* __restrict__ top_w,
    int* __restrict__ tlist, int* __restrict__ pair_pos,
    int* __restrict__ counts, int* __restrict__ offsets)
{
    __shared__ int cnt[E_], off[E_], fill[E_];
    int tid = threadIdx.x;
    if (tid < E_) { cnt[tid] = 0; fill[tid] = 0; }
    __syncthreads();
    for (int t = tid; t < T_; t += 256) {
        atomicAdd(&cnt[top_i[t * 2]], 1);
        atomicAdd(&cnt[top_i[t * 2 + 1]], 1);
    }
    __syncthreads();
    if (tid == 0) {
        int o = 0;
        for (int e = 0; e < E_; e++) { off[e] = o; o += cnt[e]; }
    }
    __syncthreads();
    for (int t = tid; t < T_; t += 256) {
        for (int j = 0; j < 2; j++) {
            int e = top_i[t * 2 + j];
            int pos = off[e] + atomicAdd(&fill[e], 1);
            tlist[pos] = t;
            pair_pos[t * 2 + j] = pos;
        }
    }
    __syncthreads();
    if (tid < E_) { counts[tid] = cnt[tid]; offsets[tid] = off[tid]; }
}

// ---------------- MoE gate+up GEMM: global_load_lds, linear LDS, KST=32 ----------------
__global__ __launch_bounds__(256) void moe_gemm_gateup(
    const __bf16* __restrict__ Xb, const __bf16* __restrict__ WgT, const __bf16* __restrict__ WuT,
    __bf16* __restrict__ act, const int* __restrict__ tlist,
    const int* __restrict__ counts, const int* __restrict__ offsets)
{
    int e = blockIdx.z;
    int cnt = counts[e], off = offsets[e];
    int m0 = blockIdx.y * MBM;
    if (m0 >= cnt) return;
    int n0 = blockIdx.x * BN;
    const __bf16* Bg = WgT + (size_t)e * H_ * I_;   // [I][H]
    const __bf16* Bu = WuT + (size_t)e * H_ * I_;
    __shared__ __bf16 As[MBM * KST];   // [128][32] linear, 8 KB
    __shared__ __bf16 Gs[BN * KST];    // [64][32] linear, 4 KB
    __shared__ __bf16 Us[BN * KST];
    __shared__ int rowidx[MBM];
    int tid = threadIdx.x;
    if (tid < MBM) {
        int rl = m0 + tid;
        rowidx[tid] = tlist[off + ((rl < cnt) ? rl : 0)];
    }
    __syncthreads();
    int lane = tid & 63, wid = tid >> 6;
    // per-lane staging sources; chunk c -> row=c>>2, colgroup=c&3 (16B)
    const __bf16* a_src[2];
#pragma unroll
    for (int i = 0; i < 2; i++) {
        int chunk = (wid * 2 + i) * 64 + lane;
        a_src[i] = Xb + (size_t)rowidx[chunk >> 2] * H_ + (chunk & 3) * 8;
    }
    int bchunk = wid * 64 + lane;
    const __bf16* g_src = Bg + (size_t)(n0 + (bchunk >> 2)) * H_ + (bchunk & 3) * 8;
    const __bf16* u_src = Bu + (size_t)(n0 + (bchunk >> 2)) * H_ + (bchunk & 3) * 8;
    f32x4 accg[2][4] = {}, accu[2][4] = {};
    int r = lane & 15, q8 = (lane >> 4) * 8;
    char* Asb = (char*)As;
    char* Gsb = (char*)Gs;
    char* Usb = (char*)Us;
    for (int kt = 0; kt < H_; kt += KST) {
        gload16(a_src[0] + kt, As + (wid * 2 + 0) * 512);
        gload16(a_src[1] + kt, As + (wid * 2 + 1) * 512);
        gload16(g_src + kt, Gs + wid * 512);
        gload16(u_src + kt, Us + wid * 512);
        __syncthreads();   // drains vmcnt(0): tiles resident
        bf16x8 af[2], gf[4], uf[4];
#pragma unroll
        for (int m = 0; m < 2; m++)
            af[m] = *(const bf16x8*)(Asb + (wid * 32 + m * 16 + r) * 64 + q8 * 2);
#pragma unroll
        for (int n = 0; n < 4; n++) {
            gf[n] = *(const bf16x8*)(Gsb + (n * 16 + r) * 64 + q8 * 2);
            uf[n] = *(const bf16x8*)(Usb + (n * 16 + r) * 64 + q8 * 2);
        }
#pragma unroll
        for (int m = 0; m < 2; m++)
#pragma unroll
            for (int n = 0; n < 4; n++) {
                accg[m][n] = __builtin_amdgcn_mfma_f32_16x16x32_bf16(af[m], gf[n], accg[m][n], 0, 0, 0);
                accu[m][n] = __builtin_amdgcn_mfma_f32_16x16x32_bf16(af[m], uf[n], accu[m][n], 0, 0, 0);
            }
        __syncthreads();   // reads done before next overwrite
    }
    int cl = lane & 15, rb = (lane >> 4) * 4;
#pragma unroll
    for (int m = 0; m < 2; m++)
#pragma unroll
        for (int n = 0; n < 4; n++)
#pragma unroll
            for (int j = 0; j < 4; j++) {
                int rl = m0 + wid * 32 + m * 16 + rb + j;
                if (rl >= cnt) continue;
                int col = n0 + n * 16 + cl;
                float g = accg[m][n][j], u = accu[m][n][j];
                float sig = 1.f / (1.f + __expf(-g));
                act[(size_t)(off + rl) * I_ + col] = (__bf16)(g * sig * u);
            }
}

// ---------------- MoE down GEMM: global_load_lds, linear LDS, KST=32 ----------------
__global__ __launch_bounds__(256) void moe_gemm_down(
    const __bf16* __restrict__ act, const __bf16* __restrict__ WdT,
    float* __restrict__ dout, const int* __restrict__ counts, const int* __restrict__ offsets)
{
    int e = blockIdx.z;
    int cnt = counts[e], off = offsets[e];
    int m0 = blockIdx.y * DBM;
    if (m0 >= cnt) return;
    int n0 = blockIdx.x * BN;
    const __bf16* Bw = WdT + (size_t)e * I_ * H_;   // [H][I]
    __shared__ __bf16 As[DBM * KST];   // [64][32] linear, 4 KB
    __shared__ __bf16 Bs[BN * KST];
    int tid = threadIdx.x;
    int lane = tid & 63, wid = tid >> 6;
    int chunk = wid * 64 + lane;      // one inst/wave per operand
    int crow = chunk >> 2, ccg = chunk & 3;
    int arow = m0 + crow; if (arow >= cnt) arow = cnt - 1;
    const __bf16* a_src = act + (size_t)(off + arow) * I_ + ccg * 8;
    const __bf16* b_src = Bw + (size_t)(n0 + crow) * I_ + ccg * 8;
    f32x4 acc[4] = {};
    int r = lane & 15, q8 = (lane >> 4) * 8;
    char* Asb = (char*)As;
    char* Bsb = (char*)Bs;
    for (int kt = 0; kt < I_; kt += KST) {
        gload16(a_src + kt, As + wid * 512);
        gload16(b_src + kt, Bs + wid * 512);
        __syncthreads();
        bf16x8 af = *(const bf16x8*)(Asb + (wid * 16 + r) * 64 + q8 * 2);
        bf16x8 bfr[4];
#pragma unroll
        for (int n = 0; n < 4; n++)
            bfr[n] = *(const bf16x8*)(Bsb + (n * 16 + r) * 64 + q8 * 2);
#pragma unroll
        for (int n = 0; n < 4; n++)
            acc[n] = __builtin_amdgcn_mfma_f32_16x16x32_bf16(af, bfr[n], acc[n], 0, 0, 0);
        __syncthreads();
    }
    int cl = lane & 15, rb = (lane >> 4) * 4;
#pragma unroll
    for (int n = 0; n < 4; n++)
#pragma unroll
        for (int j = 0; j < 4; j++) {
            int rl = m0 + wid * 16 + rb + j;
            if (rl >= cnt) continue;
            int col = n0 + n * 16 + cl;
            dout[(size_t)(off + rl) * H_ + col] = acc[n][j];
        }
}

// ---------------- Final combine ----------------
__global__ __launch_bounds__(256) void combine_kernel(
    const float* __restrict__ hres, const float* __restrict__ dout,
    const int* __restrict__ pair_pos, const float* __restrict__ top_w,
    float* __restrict__ out)
{
    int idx = blockIdx.x * 256 + threadIdx.x;
    int t = idx >> 10, d = idx & 1023;
    float v = hres[idx];
    int p0 = pair_pos[t * 2], p1 = pair_pos[t * 2 + 1];
    v += top_w[t * 2] * dout[(size_t)p0 * H_ + d]
       + top_w[t * 2 + 1] * dout[(size_t)p1 * H_ + d];
    out[idx] = v;
}

extern "C" void kernel_launch(void* const* d_in, const int* in_sizes, int n_in,
                              void* d_out, int out_size, void* d_ws, size_t ws_size,
                              hipStream_t stream) {
    const float* hidden = (const float*)d_in[0];
    const float* ln1 = (const float*)d_in[1];
    const float* wq = (const float*)d_in[2];
    const float* wk = (const float*)d_in[3];
    const float* wv = (const float*)d_in[4];
    const float* wo = (const float*)d_in[5];
    const float* ln2 = (const float*)d_in[6];
    const float* rw = (const float*)d_in[7];
    const float* wg = (const float*)d_in[8];
    const float* wu = (const float*)d_in[9];
    const float* wd = (const float*)d_in[10];
    float* out = (float*)d_out;

    char* ws = (char*)d_ws;
    size_t o = 0;
    auto alloc = [&](size_t bytes) -> void* {
        void* p = ws + o;
        o += (bytes + 255) & ~(size_t)255;
        return p;
    };
    float* xn   = (float*)alloc((size_t)T_ * H_ * 4);
    float* qb   = (float*)alloc((size_t)T_ * NH_ * HD_ * 4);
    float* kb   = (float*)alloc((size_t)T_ * NKV_ * HD_ * 4);
    float* vb   = (float*)alloc((size_t)T_ * NKV_ * HD_ * 4);
    float* hres = (float*)alloc((size_t)T_ * H_ * 4);
    int*   top_i    = (int*)alloc((size_t)T_ * 2 * 4);
    float* top_w    = (float*)alloc((size_t)T_ * 2 * 4);
    int*   pair_pos = (int*)alloc((size_t)T_ * 2 * 4);
    int*   tlist    = (int*)alloc((size_t)T_ * 2 * 4);
    int*   counts   = (int*)alloc(E_ * 4);
    int*   offsets  = (int*)alloc(E_ * 4);
    __bf16* actb  = (__bf16*)alloc((size_t)T_ * 2 * I_ * 2);
    float*  doutb = (float*)alloc((size_t)T_ * 2 * H_ * 4);
    __bf16* xnb1 = (__bf16*)alloc((size_t)T_ * H_ * 2);
    __bf16* xnb  = (__bf16*)alloc((size_t)T_ * H_ * 2);
    __bf16* attnb = (__bf16*)alloc((size_t)T_ * H_ * 2);
    __bf16* wgt = (__bf16*)alloc((size_t)E_ * H_ * I_ * 2);
    __bf16* wut = (__bf16*)alloc((size_t)E_ * H_ * I_ * 2);
    __bf16* wdt = (__bf16*)alloc((size_t)E_ * I_ * H_ * 2);
    __bf16* wqt = (__bf16*)alloc((size_t)H_ * NH_ * HD_ * 2);
    __bf16* wkt = (__bf16*)alloc((size_t)H_ * NKV_ * HD_ * 2);
    __bf16* wvt = (__bf16*)alloc((size_t)H_ * NKV_ * HD_ * 2);
    __bf16* wot = (__bf16*)alloc((size_t)NH_ * HD_ * H_ * 2);
    __bf16* qhib = (__bf16*)alloc((size_t)T_ * NH_ * HD_ * 2);
    __bf16* qlob = (__bf16*)alloc((size_t)T_ * NH_ * HD_ * 2);
    __bf16* khib = (__bf16*)alloc((size_t)T_ * NKV_ * HD_ * 2);
    __bf16* klob = (__bf16*)alloc((size_t)T_ * NKV_ * HD_ * 2);
    __bf16* vhib = (__bf16*)alloc((size_t)T_ * NKV_ * HD_ * 2);
    __bf16* vlob = (__bf16*)alloc((size_t)T_ * NKV_ * HD_ * 2);

    transpose_cvt_kernel<<<dim3(I_ / 64, H_ / 64, E_), 256, 0, stream>>>(wg, wgt, H_, I_);
    transpose_cvt_kernel<<<dim3(I_ / 64, H_ / 64, E_), 256, 0, stream>>>(wu, wut, H_, I_);
    transpose_cvt_kernel<<<dim3(H_ / 64, I_ / 64, E_), 256, 0, stream>>>(wd, wdt, I_, H_);
    transpose_cvt_kernel<<<dim3((NH_ * HD_) / 64, H_ / 64, 1), 256, 0, stream>>>(wq, wqt, H_, NH_ * HD_);
    transpose_cvt_kernel<<<dim3((NKV_ * HD_) / 64, H_ / 64, 1), 256, 0, stream>>>(wk, wkt, H_, NKV_ * HD_);
    transpose_cvt_kernel<<<dim3((NKV_ * HD_) / 64, H_ / 64, 1), 256, 0, stream>>>(wv, wvt, H_, NKV_ * HD_);
    transpose_cvt_kernel<<<dim3(H_ / 64, (NH_ * HD_) / 64, 1), 256, 0, stream>>>(wo, wot, NH_ * HD_, H_);

    rmsnorm_kernel<<<T_, 256, 0, stream>>>(hidden, ln1, xnb1, nullptr);
    gemm_bf16bt<<<dim3((NH_ * HD_) / BN, T_ / DBM), 256, 0, stream>>>(xnb1, wqt, qb, nullptr, T_, NH_ * HD_, H_);
    gemm_bf16bt<<<dim3((NKV_ * HD_) / BN, T_ / DBM), 256, 0, stream>>>(xnb1, wkt, kb, nullptr, T_, NKV_ * HD_, H_);
    gemm_bf16bt<<<dim3((NKV_ * HD_) / BN, T_ / DBM), 256, 0, stream>>>(xnb1, wvt, vb, nullptr, T_, NKV_ * HD_, H_);
    {
        int tq = T_ * NH_ * 32, tk = T_ * NKV_ * 32;
        rope_split_kernel<<<(tq + 255) / 256, 256, 0, stream>>>(qb, qhib, qlob, 0.125f, NH_, tq);
        rope_split_kernel<<<(tk + 255) / 256, 256, 0, stream>>>(kb, khib, klob, 1.0f, NKV_, tk);
        int nk8 = T_ * NKV_ * HD_ / 8;
        split_bf16_kernel<<<(nk8 + 255) / 256, 256, 0, stream>>>(vb, vhib, vlob, 1.0f, nk8);
    }
    flash_kernel<<<dim3(S_ / 16, NKV_, B_), 256, 0, stream>>>(qhib, qlob, khib, klob, vhib, vlob, attnb);
    gemm_bf16bt<<<dim3(H_ / BN, T_ / DBM), 256, 0, stream>>>(attnb, wot, hres, hidden, T_, H_, NH_ * HD_);
    rmsnorm_kernel<<<T_, 256, 0, stream>>>(hres, ln2, xnb, xn);
    router_kernel<<<T_ / 4, 256, 0, stream>>>(xn, rw, top_i, top_w);
    assign_kernel<<<1, 256, 0, stream>>>(top_i, top_w, tlist, pair_pos, counts, offsets);
    moe_gemm_gateup<<<dim3(I_ / BN, T_ / MBM, E_), 256, 0, stream>>>(xnb, wgt, wut, actb, tlist, counts, offsets);
    moe_gemm_down<<<dim3(H_ / BN, T_ / DBM, E_), 256, 0, stream>>>(actb, wdt, doutb, counts, offsets);
    combine_kernel<<<(T_ * H_) / 256, 256, 0, stream>>>(hres, doutb, pair_pos, top_w, out);
}

// Round 19
// 429.663 us; speedup vs baseline: 1.0281x; 1.0281x over previous
//
#include <hip/hip_runtime.h>
#include <hip/hip_bf16.h>
#include <math.h>

#define B_ 2
#define S_ 1024
#define H_ 1024
#define NH_ 16
#define NKV_ 4
#define HD_ 64
#define E_ 8
#define I_ 3584
#define T_ (B_*S_)

#define BM 64
#define BN 64
#define MBM 128   // gateup M-tile
#define DBM 64    // down / dense M-tile
#define MBK 64    // K-step

typedef __bf16 bf16x8 __attribute__((ext_vector_type(8)));
typedef float f32x4 __attribute__((ext_vector_type(4)));

__device__ __forceinline__ __bf16 bf_hi(float f) { return (__bf16)f; }
__device__ __forceinline__ __bf16 bf_lo(float f, __bf16 h) { return (__bf16)(f - (float)h); }

// XOR swizzle for [rows][64 bf16] tiles (128 B row stride).
__device__ __forceinline__ int swz128(int row, int col) {
    return (row * 128 + col * 2) ^ ((row & 7) << 4);
}

// ---------------- fp32 -> (hi,lo) bf16 planes, optional scale ----------------
__global__ __launch_bounds__(256) void split_bf16_kernel(
    const float* __restrict__ src, __bf16* __restrict__ hi, __bf16* __restrict__ lo,
    float scale, int n8)
{
    int idx = blockIdx.x * 256 + threadIdx.x;
    if (idx >= n8) return;
    const float4* s = (const float4*)src + (size_t)idx * 2;
    float4 a = s[0], b = s[1];
    float f[8] = {a.x, a.y, a.z, a.w, b.x, b.y, b.z, b.w};
    bf16x8 vh, vl;
#pragma unroll
    for (int i = 0; i < 8; i++) {
        float x = f[i] * scale;
        __bf16 h = bf_hi(x);
        vh[i] = h;
        vl[i] = bf_lo(x, h);
    }
    ((bf16x8*)hi)[idx] = vh;
    ((bf16x8*)lo)[idx] = vl;
}

// ---------------- fp32 [M][N] -> bf16 transposed [N][M], per expert/z-slice ----------------
__global__ __launch_bounds__(256) void transpose_cvt_kernel(
    const float* __restrict__ src, __bf16* __restrict__ dst, int M, int N)
{
    int e = blockIdx.z;
    src += (size_t)e * M * N;
    dst += (size_t)e * M * N;
    int n0 = blockIdx.x * 64, m0 = blockIdx.y * 64;
    __shared__ __bf16 Ts[64][72];
    int tid = threadIdx.x;
#pragma unroll
    for (int i = 0; i < 16; i++) {
        int row = i * 4 + (tid >> 6);
        int col = tid & 63;
        Ts[row][col] = (__bf16)src[(size_t)(m0 + row) * N + n0 + col];
    }
    __syncthreads();
#pragma unroll
    for (int j = 0; j < 2; j++) {
        int n = (tid >> 3) + j * 32;
        int k8 = (tid & 7) * 8;
        bf16x8 v;
#pragma unroll
        for (int ii = 0; ii < 8; ii++) v[ii] = Ts[k8 + ii][n];
        *(bf16x8*)(dst + (size_t)(n0 + n) * M + m0 + k8) = v;
    }
}

// ---------------- RMSNorm: bf16 out (+ optional fp32 out) ----------------
__global__ __launch_bounds__(256) void rmsnorm_kernel(
    const float* __restrict__ x, const float* __restrict__ w,
    __bf16* __restrict__ outb, float* __restrict__ outf)
{
    int row = blockIdx.x;
    int tid = threadIdx.x;
    const float* xr = x + (size_t)row * H_;
    float vals[4];
    float ss = 0.f;
#pragma unroll
    for (int i = 0; i < 4; i++) {
        vals[i] = xr[tid + 256 * i];
        ss += vals[i] * vals[i];
    }
#pragma unroll
    for (int off = 32; off; off >>= 1) ss += __shfl_xor(ss, off);
    __shared__ float red[4];
    int wid = tid >> 6;
    if ((tid & 63) == 0) red[wid] = ss;
    __syncthreads();
    float tot = red[0] + red[1] + red[2] + red[3];
    float scale = rsqrtf(tot * (1.0f / H_) + 1e-5f);
#pragma unroll
    for (int i = 0; i < 4; i++) {
        float y = vals[i] * scale * w[tid + 256 * i];
        outb[(size_t)row * H_ + tid + 256 * i] = (__bf16)y;
        if (outf) outf[(size_t)row * H_ + tid + 256 * i] = y;
    }
}

// ---------------- Dense bf16 GEMM: A[M][K] bf16, BT[N][K] bf16 -> C[M][N] f32 (+res) ----
__global__ __launch_bounds__(256) void gemm_bf16bt(
    const __bf16* __restrict__ A, const __bf16* __restrict__ BT,
    float* __restrict__ C, const float* __restrict__ res,
    int M, int N, int Kd)
{
    int m0 = blockIdx.y * DBM;
    int n0 = blockIdx.x * BN;
    __shared__ __bf16 As[2][DBM * MBK];
    __shared__ __bf16 Bs[2][BN * MBK];
    int tid = threadIdx.x;
    int lane = tid & 63, wid = tid >> 6;
    f32x4 acc[4] = {};
    int ar = tid >> 2, ac = (tid & 3) * 16;
    int bn = tid >> 2, bc = (tid & 3) * 16;
    const __bf16* abase = A + (size_t)(m0 + ar) * Kd + ac;
    const __bf16* bbase = BT + (size_t)(n0 + bn) * Kd + bc;
    {
        char* Asb = (char*)As[0];
        char* Bsb = (char*)Bs[0];
#pragma unroll
        for (int g = 0; g < 2; g++) {
            *(bf16x8*)(Asb + swz128(ar, ac + g * 8)) = *(const bf16x8*)(abase + g * 8);
            *(bf16x8*)(Bsb + swz128(bn, bc + g * 8)) = *(const bf16x8*)(bbase + g * 8);
        }
    }
    bf16x8 pa[2], pb[2];
    if (Kd > MBK) {
#pragma unroll
        for (int g = 0; g < 2; g++) {
            pa[g] = *(const bf16x8*)(abase + MBK + g * 8);
            pb[g] = *(const bf16x8*)(bbase + MBK + g * 8);
        }
    }
    int cur = 0;
    int r = lane & 15, q8 = (lane >> 4) * 8;
    for (int kt = 0; kt < Kd; kt += MBK) {
        __syncthreads();
        char* Asb = (char*)As[cur];
        char* Bsb = (char*)Bs[cur];
#pragma unroll
        for (int kk = 0; kk < 2; kk++) {
            bf16x8 af = *(const bf16x8*)(Asb + swz128(wid * 16 + r, kk * 32 + q8));
            bf16x8 bfr[4];
#pragma unroll
            for (int n = 0; n < 4; n++)
                bfr[n] = *(const bf16x8*)(Bsb + swz128(n * 16 + r, kk * 32 + q8));
#pragma unroll
            for (int n = 0; n < 4; n++)
                acc[n] = __builtin_amdgcn_mfma_f32_16x16x32_bf16(af, bfr[n], acc[n], 0, 0, 0);
        }
        int kn = kt + MBK;
        if (kn < Kd) {
            char* Asw = (char*)As[cur ^ 1];
            char* Bsw = (char*)Bs[cur ^ 1];
#pragma unroll
            for (int g = 0; g < 2; g++) {
                *(bf16x8*)(Asw + swz128(ar, ac + g * 8)) = pa[g];
                *(bf16x8*)(Bsw + swz128(bn, bc + g * 8)) = pb[g];
            }
            int k2 = kn + MBK;
            if (k2 < Kd) {
#pragma unroll
                for (int g = 0; g < 2; g++) {
                    pa[g] = *(const bf16x8*)(abase + k2 + g * 8);
                    pb[g] = *(const bf16x8*)(bbase + k2 + g * 8);
                }
            }
            cur ^= 1;
        }
    }
    int cl = lane & 15, rb = (lane >> 4) * 4;
#pragma unroll
    for (int n = 0; n < 4; n++)
#pragma unroll
        for (int j = 0; j < 4; j++) {
            int row = m0 + wid * 16 + rb + j;
            int col = n0 + n * 16 + cl;
            size_t o = (size_t)row * N + col;
            float v = acc[n][j];
            if (res) v += res[o];
            C[o] = v;
        }
}

// ---------------- RoPE + hi/lo split ----------------
__global__ void rope_split_kernel(
    const float* __restrict__ x, __bf16* __restrict__ hi, __bf16* __restrict__ lo,
    float scale, int heads, int total)
{
    int idx = blockIdx.x * blockDim.x + threadIdx.x;
    if (idx >= total) return;
    int j = idx & 31;
    int th = idx >> 5;
    int h = th % heads;
    int t = th / heads;
    int s = t & (S_ - 1);
    float inv = powf(1e6f, -(float)j / 32.0f);
    float ang = (float)s * inv;
    float c = cosf(ang), sn = sinf(ang);
    size_t base = (size_t)t * heads * HD_ + (size_t)h * HD_;
    float x1 = x[base + j], x2 = x[base + 32 + j];
    float y1 = (x1 * c - x2 * sn) * scale;
    float y2 = (x2 * c + x1 * sn) * scale;
    __bf16 h1 = bf_hi(y1), h2 = bf_hi(y2);
    hi[base + j] = h1;       lo[base + j] = bf_lo(y1, h1);
    hi[base + 32 + j] = h2;  lo[base + 32 + j] = bf_lo(y2, h2);
}

// ---------------- MFMA flash attention — hi/lo planes, bf16 attn out ----------------
#define LP 72
__global__ __launch_bounds__(256) void flash_kernel(
    const __bf16* __restrict__ qhi, const __bf16* __restrict__ qlo_g,
    const __bf16* __restrict__ khi, const __bf16* __restrict__ klo,
    const __bf16* __restrict__ vhi, const __bf16* __restrict__ vlo,
    __bf16* __restrict__ o)
{
    __shared__ __bf16 Ks [64][LP];
    __shared__ __bf16 Ksl[64][LP];
    __shared__ __bf16 Vt [64][LP];
    __shared__ __bf16 Vtl[64][LP];
    __shared__ __bf16 Pl [4][16][LP];
    __shared__ __bf16 Pll[4][16][LP];

    int tid = threadIdx.x;
    int lane = tid & 63, wid = tid >> 6;
    int qr = lane & 15, quad = lane >> 4;
    int qt = (S_ / 16 - 1) - blockIdx.x;
    int kvh = blockIdx.y, b = blockIdx.z;
    int h = kvh * 4 + wid;
    int s0 = qt * 16;

    size_t qoff = ((size_t)(b * S_ + s0 + qr) * NH_ + h) * HD_ + quad * 8;
    bf16x8 qf[2], qlo[2];
#pragma unroll
    for (int ks = 0; ks < 2; ks++) {
        qf[ks]  = *(const bf16x8*)(qhi  + qoff + ks * 32);
        qlo[ks] = *(const bf16x8*)(qlo_g + qoff + ks * 32);
    }

    float m_run[4], l_run[4];
    f32x4 o_acc[4] = {};
#pragma unroll
    for (int j = 0; j < 4; j++) { m_run[j] = -1e30f; l_run[j] = 0.f; }

    int skey = tid >> 2, shd0 = (tid & 3) * 16;
    int vhd = tid & 63, vkey0 = (tid >> 6) * 16;

    for (int kt = 0; kt <= s0 + 15; kt += 64) {
        __syncthreads();
        {
            size_t koff = ((size_t)(b * S_ + kt + skey) * NKV_ + kvh) * HD_ + shd0;
            *(bf16x8*)&Ks [skey][shd0]     = *(const bf16x8*)(khi + koff);
            *(bf16x8*)&Ks [skey][shd0 + 8] = *(const bf16x8*)(khi + koff + 8);
            *(bf16x8*)&Ksl[skey][shd0]     = *(const bf16x8*)(klo + koff);
            *(bf16x8*)&Ksl[skey][shd0 + 8] = *(const bf16x8*)(klo + koff + 8);
        }
        {
            const __bf16* vh = vhi + ((size_t)(b * S_ + kt + vkey0) * NKV_ + kvh) * HD_ + vhd;
            const __bf16* vl = vlo + ((size_t)(b * S_ + kt + vkey0) * NKV_ + kvh) * HD_ + vhd;
            bf16x8 th0, th1, tl0, tl1;
#pragma unroll
            for (int i = 0; i < 8; i++) {
                th0[i] = vh[(size_t)i * (NKV_ * HD_)];
                th1[i] = vh[(size_t)(i + 8) * (NKV_ * HD_)];
                tl0[i] = vl[(size_t)i * (NKV_ * HD_)];
                tl1[i] = vl[(size_t)(i + 8) * (NKV_ * HD_)];
            }
            *(bf16x8*)&Vt [vhd][vkey0]     = th0;
            *(bf16x8*)&Vt [vhd][vkey0 + 8] = th1;
            *(bf16x8*)&Vtl[vhd][vkey0]     = tl0;
            *(bf16x8*)&Vtl[vhd][vkey0 + 8] = tl1;
        }
        __syncthreads();

        f32x4 sc4[4];
#pragma unroll
        for (int sub = 0; sub < 4; sub++) {
            int krow = sub * 16 + qr;
            bf16x8 kh0 = *(const bf16x8*)&Ks [krow][quad * 8];
            bf16x8 kh1 = *(const bf16x8*)&Ks [krow][32 + quad * 8];
            bf16x8 kl0 = *(const bf16x8*)&Ksl[krow][quad * 8];
            bf16x8 kl1 = *(const bf16x8*)&Ksl[krow][32 + quad * 8];
            f32x4 z = {};
            z = __builtin_amdgcn_mfma_f32_16x16x32_bf16(qf[0],  kh0, z, 0, 0, 0);
            z = __builtin_amdgcn_mfma_f32_16x16x32_bf16(qf[1],  kh1, z, 0, 0, 0);
            z = __builtin_amdgcn_mfma_f32_16x16x32_bf16(qlo[0], kh0, z, 0, 0, 0);
            z = __builtin_amdgcn_mfma_f32_16x16x32_bf16(qlo[1], kh1, z, 0, 0, 0);
            z = __builtin_amdgcn_mfma_f32_16x16x32_bf16(qf[0],  kl0, z, 0, 0, 0);
            z = __builtin_amdgcn_mfma_f32_16x16x32_bf16(qf[1],  kl1, z, 0, 0, 0);
            sc4[sub] = z;
        }
        if (kt + 63 > s0) {
#pragma unroll
            for (int sub = 0; sub < 4; sub++)
#pragma unroll
                for (int j = 0; j < 4; j++) {
                    int key = kt + sub * 16 + qr;
                    int row = s0 + quad * 4 + j;
                    if (key > row) sc4[sub][j] = -1e30f;
                }
        }
#pragma unroll
        for (int j = 0; j < 4; j++) {
            float mx = fmaxf(fmaxf(sc4[0][j], sc4[1][j]), fmaxf(sc4[2][j], sc4[3][j]));
#pragma unroll
            for (int off = 1; off < 16; off <<= 1) mx = fmaxf(mx, __shfl_xor(mx, off));
            float mn = fmaxf(m_run[j], mx);
            float scale = __expf(m_run[j] - mn);
            m_run[j] = mn;
            float rs = 0.f;
#pragma unroll
            for (int sub = 0; sub < 4; sub++) {
                float pe = __expf(sc4[sub][j] - mn);
                sc4[sub][j] = pe;
                rs += pe;
            }
#pragma unroll
            for (int off = 1; off < 16; off <<= 1) rs += __shfl_xor(rs, off);
            l_run[j] = l_run[j] * scale + rs;
#pragma unroll
            for (int sub = 0; sub < 4; sub++) o_acc[sub][j] *= scale;
        }
#pragma unroll
        for (int sub = 0; sub < 4; sub++)
#pragma unroll
            for (int j = 0; j < 4; j++) {
                float pe = sc4[sub][j];
                __bf16 hh = bf_hi(pe);
                Pl [wid][quad * 4 + j][sub * 16 + qr] = hh;
                Pll[wid][quad * 4 + j][sub * 16 + qr] = bf_lo(pe, hh);
            }
        __syncthreads();
        bf16x8 ph0 = *(const bf16x8*)&Pl [wid][qr][quad * 8];
        bf16x8 ph1 = *(const bf16x8*)&Pl [wid][qr][32 + quad * 8];
        bf16x8 pl0 = *(const bf16x8*)&Pll[wid][qr][quad * 8];
        bf16x8 pl1 = *(const bf16x8*)&Pll[wid][qr][32 + quad * 8];
#pragma unroll
        for (int sub = 0; sub < 4; sub++) {
            int vrow = sub * 16 + qr;
            bf16x8 vh0 = *(const bf16x8*)&Vt [vrow][quad * 8];
            bf16x8 vh1 = *(const bf16x8*)&Vt [vrow][32 + quad * 8];
            bf16x8 vl0 = *(const bf16x8*)&Vtl[vrow][quad * 8];
            bf16x8 vl1 = *(const bf16x8*)&Vtl[vrow][32 + quad * 8];
            o_acc[sub] = __builtin_amdgcn_mfma_f32_16x16x32_bf16(ph0, vh0, o_acc[sub], 0, 0, 0);
            o_acc[sub] = __builtin_amdgcn_mfma_f32_16x16x32_bf16(ph1, vh1, o_acc[sub], 0, 0, 0);
            o_acc[sub] = __builtin_amdgcn_mfma_f32_16x16x32_bf16(ph0, vl0, o_acc[sub], 0, 0, 0);
            o_acc[sub] = __builtin_amdgcn_mfma_f32_16x16x32_bf16(ph1, vl1, o_acc[sub], 0, 0, 0);
            o_acc[sub] = __builtin_amdgcn_mfma_f32_16x16x32_bf16(pl0, vh0, o_acc[sub], 0, 0, 0);
            o_acc[sub] = __builtin_amdgcn_mfma_f32_16x16x32_bf16(pl1, vh1, o_acc[sub], 0, 0, 0);
        }
    }
#pragma unroll
    for (int j = 0; j < 4; j++) {
        float inv = 1.f / l_run[j];
        int row = s0 + quad * 4 + j;
#pragma unroll
        for (int sub = 0; sub < 4; sub++)
            o[((size_t)(b * S_ + row) * NH_ + h) * HD_ + sub * 16 + qr] = (__bf16)(o_acc[sub][j] * inv);
    }
}

// ---------------- Router ----------------
__global__ __launch_bounds__(256) void router_kernel(
    const float* __restrict__ xn, const float* __restrict__ rw,
    int* __restrict__ top_i, float* __restrict__ top_w)
{
    int wid = threadIdx.x >> 6, lane = threadIdx.x & 63;
    int t = blockIdx.x * 4 + wid;
    const float* xr = xn + (size_t)t * H_;
    float acc[E_] = {};
    for (int c = 0; c < H_ / 64; c++) {
        float xd = xr[c * 64 + lane];
        const float* wrow = rw + (size_t)(c * 64 + lane) * E_;
#pragma unroll
        for (int e = 0; e < E_; e++) acc[e] += xd * wrow[e];
    }
#pragma unroll
    for (int e = 0; e < E_; e++) {
        float r = acc[e];
#pragma unroll
        for (int off = 32; off; off >>= 1) r += __shfl_xor(r, off);
        acc[e] = r;
    }
    if (lane == 0) {
        float mx = acc[0];
        for (int e = 1; e < E_; e++) mx = fmaxf(mx, acc[e]);
        float p[E_], sum = 0.f;
        for (int e = 0; e < E_; e++) { p[e] = __expf(acc[e] - mx); sum += p[e]; }
        float inv_s = 1.f / sum;
        for (int e = 0; e < E_; e++) p[e] *= inv_s;
        int i0 = 0;
        for (int e = 1; e < E_; e++) if (p[e] > p[i0]) i0 = e;
        int i1 = (i0 == 0) ? 1 : 0;
        for (int e = 0; e < E_; e++) if (e != i0 && p[e] > p[i1]) i1 = e;
        float v0 = p[i0], v1 = p[i1], inv = 1.f / (v0 + v1);
        top_i[t * 2] = i0; top_i[t * 2 + 1] = i1;
        top_w[t * 2] = v0 * inv; top_w[t * 2 + 1] = v1 * inv;
    }
}

// ---------------- Assignment ----------------
__global__ void assign_kernel(
    const int* __restrict__ top_i, const float* __restrict__ top_w,
    int* __restrict__ tlist, int* __restrict__ pair_pos,
    int* __restrict__ counts, int* __restrict__ offsets)
{
    __shared__ int cnt[E_], off[E_], fill[E_];
    int tid = threadIdx.x;
    if (tid < E_) { cnt[tid] = 0; fill[tid] = 0; }
    __syncthreads();
    for (int t = tid; t < T_; t += 256) {
        atomicAdd(&cnt[top_i[t * 2]], 1);
        atomicAdd(&cnt[top_i[t * 2 + 1]], 1);
    }
    __syncthreads();
    if (tid == 0) {
        int o = 0;
        for (int e = 0; e < E_; e++) { off[e] = o; o += cnt[e]; }
    }
    __syncthreads();
    for (int t = tid; t < T_; t += 256) {
        for (int j = 0; j < 2; j++) {
            int e = top_i[t * 2 + j];
            int pos = off[e] + atomicAdd(&fill[e], 1);
            tlist[pos] = t;
            pair_pos[t * 2 + j] = pos;
        }
    }
    __syncthreads();
    if (tid < E_) { counts[tid] = cnt[tid]; offsets[tid] = off[tid]; }
}

// ---------------- MoE gate+up GEMM: r12/r17 config (dbuf, 1 barrier/K-step) ----------------
__global__ __launch_bounds__(256) void moe_gemm_gateup(
    const __bf16* __restrict__ Xb, const __bf16* __restrict__ WgT, const __bf16* __restrict__ WuT,
    __bf16* __restrict__ act, const int* __restrict__ tlist,
    const int* __restrict__ counts, const int* __restrict__ offsets)
{
    int e = blockIdx.z;
    int cnt = counts[e], off = offsets[e];
    int m0 = blockIdx.y * MBM;
    if (m0 >= cnt) return;
    int n0 = blockIdx.x * BN;
    const __bf16* Bg = WgT + (size_t)e * H_ * I_;
    const __bf16* Bu = WuT + (size_t)e * H_ * I_;
    __shared__ __bf16 As[2][MBM * MBK];
    __shared__ __bf16 Gs[2][BN * MBK];
    __shared__ __bf16 Us[2][BN * MBK];
    __shared__ int rowidx[MBM];
    int tid = threadIdx.x;
    if (tid < MBM) {
        int rl = m0 + tid;
        rowidx[tid] = tlist[off + ((rl < cnt) ? rl : 0)];
    }
    __syncthreads();
    int lane = tid & 63, wid = tid >> 6;
    f32x4 accg[2][4] = {}, accu[2][4] = {};
    int ar = tid >> 1, ac = (tid & 1) * 32;
    int bn = tid >> 2, bc = (tid & 3) * 16;
    const __bf16* abase = Xb + (size_t)rowidx[ar] * H_ + ac;
    const __bf16* gbase = Bg + (size_t)(n0 + bn) * H_ + bc;
    const __bf16* ubase = Bu + (size_t)(n0 + bn) * H_ + bc;
    {
        char* Asb = (char*)As[0];
        char* Gsb = (char*)Gs[0];
        char* Usb = (char*)Us[0];
#pragma unroll
        for (int g = 0; g < 4; g++)
            *(bf16x8*)(Asb + swz128(ar, ac + g * 8)) = *(const bf16x8*)(abase + g * 8);
#pragma unroll
        for (int g = 0; g < 2; g++) {
            *(bf16x8*)(Gsb + swz128(bn, bc + g * 8)) = *(const bf16x8*)(gbase + g * 8);
            *(bf16x8*)(Usb + swz128(bn, bc + g * 8)) = *(const bf16x8*)(ubase + g * 8);
        }
    }
    bf16x8 pa[4], pg[2], pu[2];
    if (H_ > MBK) {
#pragma unroll
        for (int g = 0; g < 4; g++) pa[g] = *(const bf16x8*)(abase + MBK + g * 8);
#pragma unroll
        for (int g = 0; g < 2; g++) {
            pg[g] = *(const bf16x8*)(gbase + MBK + g * 8);
            pu[g] = *(const bf16x8*)(ubase + MBK + g * 8);
        }
    }
    int cur = 0;
    int r = lane & 15, q8 = (lane >> 4) * 8;
    for (int kt = 0; kt < H_; kt += MBK) {
        __syncthreads();
        char* Asb = (char*)As[cur];
        char* Gsb = (char*)Gs[cur];
        char* Usb = (char*)Us[cur];
#pragma unroll
        for (int kk = 0; kk < 2; kk++) {
            bf16x8 af[2], gf[4], uf[4];
#pragma unroll
            for (int m = 0; m < 2; m++)
                af[m] = *(const bf16x8*)(Asb + swz128(wid * 32 + m * 16 + r, kk * 32 + q8));
#pragma unroll
            for (int n = 0; n < 4; n++) {
                gf[n] = *(const bf16x8*)(Gsb + swz128(n * 16 + r, kk * 32 + q8));
                uf[n] = *(const bf16x8*)(Usb + swz128(n * 16 + r, kk * 32 + q8));
            }
#pragma unroll
            for (int m = 0; m < 2; m++)
#pragma unroll
                for (int n = 0; n < 4; n++) {
                    accg[m][n] = __builtin_amdgcn_mfma_f32_16x16x32_bf16(af[m], gf[n], accg[m][n], 0, 0, 0);
                    accu[m][n] = __builtin_amdgcn_mfma_f32_16x16x32_bf16(af[m], uf[n], accu[m][n], 0, 0, 0);
                }
        }
        int kn = kt + MBK;
        if (kn < H_) {
            char* Asw = (char*)As[cur ^ 1];
            char* Gsw = (char*)Gs[cur ^ 1];
            char* Usw = (char*)Us[cur ^ 1];
#pragma unroll
            for (int g = 0; g < 4; g++) *(bf16x8*)(Asw + swz128(ar, ac + g * 8)) = pa[g];
#pragma unroll
            for (int g = 0; g < 2; g++) {
                *(bf16x8*)(Gsw + swz128(bn, bc + g * 8)) = pg[g];
                *(bf16x8*)(Usw + swz128(bn, bc + g * 8)) = pu[g];
            }
            int k2 = kn + MBK;
            if (k2 < H_) {
#pragma unroll
                for (int g = 0; g < 4; g++) pa[g] = *(const bf16x8*)(abase + k2 + g * 8);
#pragma unroll
                for (int g = 0; g < 2; g++) {
                    pg[g] = *(const bf16x8*)(gbase + k2 + g * 8);
                    pu[g] = *(const bf16x8*)(ubase + k2 + g * 8);
                }
            }
            cur ^= 1;
        }
    }
    int cl = lane & 15, rb = (lane >> 4) * 4;
#pragma unroll
    for (int m = 0; m < 2; m++)
#pragma unroll
        for (int n = 0; n < 4; n++)
#pragma unroll
            for (int j = 0; j < 4; j++) {
                int rl = m0 + wid * 32 + m * 16 + rb + j;
                if (rl >= cnt) continue;
                int col = n0 + n * 16 + cl;
                float g = accg[m][n][j], u = accu[m][n][j];
                float sig = 1.f / (1.f + __expf(-g));
                act[(size_t)(off + rl) * I_ + col] = (__bf16)(g * sig * u);
            }
}

// ---------------- MoE down GEMM: r12/r17 config, bf16 dout ----------------
__global__ __launch_bounds__(256) void moe_gemm_down(
    const __bf16* __restrict__ act, const __bf16* __restrict__ WdT,
    __bf16* __restrict__ dout, const int* __restrict__ counts, const int* __restrict__ offsets)
{
    int e = blockIdx.z;
    int cnt = counts[e], off = offsets[e];
    int m0 = blockIdx.y * DBM;
    if (m0 >= cnt) return;
    int n0 = blockIdx.x * BN;
    const __bf16* Bw = WdT + (size_t)e * I_ * H_;
    __shared__ __bf16 As[2][DBM * MBK];
    __shared__ __bf16 Bs[2][BN * MBK];
    int tid = threadIdx.x;
    int lane = tid & 63, wid = tid >> 6;
    f32x4 acc[4] = {};
    int ar = tid >> 2, ac = (tid & 3) * 16;
    int bn = tid >> 2, bc = (tid & 3) * 16;
    int arow = m0 + ar; if (arow >= cnt) arow = cnt - 1;
    const __bf16* abase = act + (size_t)(off + arow) * I_ + ac;
    const __bf16* bbase = Bw + (size_t)(n0 + bn) * I_ + bc;
    {
        char* Asb = (char*)As[0];
        char* Bsb = (char*)Bs[0];
#pragma unroll
        for (int g = 0; g < 2; g++) {
            *(bf16x8*)(Asb + swz128(ar, ac + g * 8)) = *(const bf16x8*)(abase + g * 8);
            *(bf16x8*)(Bsb + swz128(bn, bc + g * 8)) = *(const bf16x8*)(bbase + g * 8);
        }
    }
    bf16x8 pa[2], pb[2];
    if (I_ > MBK) {
#pragma unroll
        for (int g = 0; g < 2; g++) {
            pa[g] = *(const bf16x8*)(abase + MBK + g * 8);
            pb[g] = *(const bf16x8*)(bbase + MBK + g * 8);
        }
    }
    int cur = 0;
    int r = lane & 15, q8 = (lane >> 4) * 8;
    for (int kt = 0; kt < I_; kt += MBK) {
        __syncthreads();
        char* Asb = (char*)As[cur];
        char* Bsb = (char*)Bs[cur];
#pragma unroll
        for (int kk = 0; kk < 2; kk++) {
            bf16x8 af = *(const bf16x8*)(Asb + swz128(wid * 16 + r, kk * 32 + q8));
            bf16x8 bfr[4];
#pragma unroll
            for (int n = 0; n < 4; n++)
                bfr[n] = *(const bf16x8*)(Bsb + swz128(n * 16 + r, kk * 32 + q8));
#pragma unroll
            for (int n = 0; n < 4; n++)
                acc[n] = __builtin_amdgcn_mfma_f32_16x16x32_bf16(af, bfr[n], acc[n], 0, 0, 0);
        }
        int kn = kt + MBK;
        if (kn < I_) {
            char* Asw = (char*)As[cur ^ 1];
            char* Bsw = (char*)Bs[cur ^ 1];
#pragma unroll
            for (int g = 0; g < 2; g++) {
                *(bf16x8*)(Asw + swz128(ar, ac + g * 8)) = pa[g];
                *(bf16x8*)(Bsw + swz128(bn, bc + g * 8)) = pb[g];
            }
            int k2 = kn + MBK;
            if (k2 < I_) {
#pragma unroll
                for (int g = 0; g < 2; g++) {
                    pa[g] = *(const bf16x8*)(abase + k2 + g * 8);
                    pb[g] = *(const bf16x8*)(bbase + k2 + g * 8);
                }
            }
            cur ^= 1;
        }
    }
    int cl = lane & 15, rb = (lane >> 4) * 4;
#pragma unroll
    for (int n = 0; n < 4; n++)
#pragma unroll
        for (int j = 0; j < 4; j++) {
            int rl = m0 + wid * 16 + rb + j;
            if (rl >= cnt) continue;
            int col = n0 + n * 16 + cl;
            dout[(size_t)(off + rl) * H_ + col] = (__bf16)acc[n][j];
        }
}

// ---------------- Final combine (bf16 dout) ----------------
__global__ __launch_bounds__(256) void combine_kernel(
    const float* __restrict__ hres, const __bf16* __restrict__ dout,
    const int* __restrict__ pair_pos, const float* __restrict__ top_w,
    float* __restrict__ out)
{
    int idx = blockIdx.x * 256 + threadIdx.x;
    int t = idx >> 10, d = idx & 1023;
    float v = hres[idx];
    int p0 = pair_pos[t * 2], p1 = pair_pos[t * 2 + 1];
    v += top_w[t * 2] * (float)dout[(size_t)p0 * H_ + d]
       + top_w[t * 2 + 1] * (float)dout[(size_t)p1 * H_ + d];
    out[idx] = v;
}

extern "C" void kernel_launch(void* const* d_in, const int* in_sizes, int n_in,
                              void* d_out, int out_size, void* d_ws, size_t ws_size,
                              hipStream_t stream) {
    const float* hidden = (const float*)d_in[0];
    const float* ln1 = (const float*)d_in[1];
    const float* wq = (const float*)d_in[2];
    const float* wk = (const float*)d_in[3];
    const float* wv = (const float*)d_in[4];
    const float* wo = (const float*)d_in[5];
    const float* ln2 = (const float*)d_in[6];
    const float* rw = (const float*)d_in[7];
    const float* wg = (const float*)d_in[8];
    const float* wu = (const float*)d_in[9];
    const float* wd = (const float*)d_in[10];
    float* out = (float*)d_out;

    char* ws = (char*)d_ws;
    size_t o = 0;
    auto alloc = [&](size_t bytes) -> void* {
        void* p = ws + o;
        o += (bytes + 255) & ~(size_t)255;
        return p;
    };
    float* xn   = (float*)alloc((size_t)T_ * H_ * 4);
    float* qb   = (float*)alloc((size_t)T_ * NH_ * HD_ * 4);
    float* kb   = (float*)alloc((size_t)T_ * NKV_ * HD_ * 4);
    float* vb   = (float*)alloc((size_t)T_ * NKV_ * HD_ * 4);
    float* hres = (float*)alloc((size_t)T_ * H_ * 4);
    int*   top_i    = (int*)alloc((size_t)T_ * 2 * 4);
    float* top_w    = (float*)alloc((size_t)T_ * 2 * 4);
    int*   pair_pos = (int*)alloc((size_t)T_ * 2 * 4);
    int*   tlist    = (int*)alloc((size_t)T_ * 2 * 4);
    int*   counts   = (int*)alloc(E_ * 4);
    int*   offsets  = (int*)alloc(E_ * 4);
    __bf16* actb  = (__bf16*)alloc((size_t)T_ * 2 * I_ * 2);
    __bf16* doutb = (__bf16*)alloc((size_t)T_ * 2 * H_ * 2);
    __bf16* xnb1 = (__bf16*)alloc((size_t)T_ * H_ * 2);
    __bf16* xnb  = (__bf16*)alloc((size_t)T_ * H_ * 2);
    __bf16* attnb = (__bf16*)alloc((size_t)T_ * H_ * 2);
    __bf16* wgt = (__bf16*)alloc((size_t)E_ * H_ * I_ * 2);
    __bf16* wut = (__bf16*)alloc((size_t)E_ * H_ * I_ * 2);
    __bf16* wdt = (__bf16*)alloc((size_t)E_ * I_ * H_ * 2);
    __bf16* wqt = (__bf16*)alloc((size_t)H_ * NH_ * HD_ * 2);
    __bf16* wkt = (__bf16*)alloc((size_t)H_ * NKV_ * HD_ * 2);
    __bf16* wvt = (__bf16*)alloc((size_t)H_ * NKV_ * HD_ * 2);
    __bf16* wot = (__bf16*)alloc((size_t)NH_ * HD_ * H_ * 2);
    __bf16* qhib = (__bf16*)alloc((size_t)T_ * NH_ * HD_ * 2);
    __bf16* qlob = (__bf16*)alloc((size_t)T_ * NH_ * HD_ * 2);
    __bf16* khib = (__bf16*)alloc((size_t)T_ * NKV_ * HD_ * 2);
    __bf16* klob = (__bf16*)alloc((size_t)T_ * NKV_ * HD_ * 2);
    __bf16* vhib = (__bf16*)alloc((size_t)T_ * NKV_ * HD_ * 2);
    __bf16* vlob = (__bf16*)alloc((size_t)T_ * NKV_ * HD_ * 2);

    transpose_cvt_kernel<<<dim3(I_ / 64, H_ / 64, E_), 256, 0, stream>>>(wg, wgt, H_, I_);
    transpose_cvt_kernel<<<dim3(I_ / 64, H_ / 64, E_), 256, 0, stream>>>(wu, wut, H_, I_);
    transpose_cvt_kernel<<<dim3(H_ / 64, I_ / 64, E_), 256, 0, stream>>>(wd, wdt, I_, H_);
    transpose_cvt_kernel<<<dim3((NH_ * HD_) / 64, H_ / 64, 1), 256, 0, stream>>>(wq, wqt, H_, NH_ * HD_);
    transpose_cvt_kernel<<<dim3((NKV_ * HD_) / 64, H_ / 64, 1), 256, 0, stream>>>(wk, wkt, H_, NKV_ * HD_);
    transpose_cvt_kernel<<<dim3((NKV_ * HD_) / 64, H_ / 64, 1), 256, 0, stream>>>(wv, wvt, H_, NKV_ * HD_);
    transpose_cvt_kernel<<<dim3(H_ / 64, (NH_ * HD_) / 64, 1), 256, 0, stream>>>(wo, wot, NH_ * HD_, H_);

    rmsnorm_kernel<<<T_, 256, 0, stream>>>(hidden, ln1, xnb1, nullptr);
    gemm_bf16bt<<<dim3((NH_ * HD_) / BN, T_ / DBM), 256, 0, stream>>>(xnb1, wqt, qb, nullptr, T_, NH_ * HD_, H_);
    gemm_bf16bt<<<dim3((NKV_ * HD_) / BN, T_ / DBM), 256, 0, stream>>>(xnb1, wkt, kb, nullptr, T_, NKV_ * HD_, H_);
    gemm_bf16bt<<<dim3((NKV_ * HD_) / BN, T_ / DBM), 256, 0, stream>>>(xnb1, wvt, vb, nullptr, T_, NKV_ * HD_, H_);
    {
        int tq = T_ * NH_ * 32, tk = T_ * NKV_ * 32;
        rope_split_kernel<<<(tq + 255) / 256, 256, 0, stream>>>(qb, qhib, qlob, 0.125f, NH_, tq);
        rope_split_kernel<<<(tk + 255) / 256, 256, 0, stream>>>(kb, khib, klob, 1.0f, NKV_, tk);
        int nk8 = T_ * NKV_ * HD_ / 8;
        split_bf16_kernel<<<(nk8 + 255) / 256, 256, 0, stream>>>(vb, vhib, vlob, 1.0f, nk8);
    }
    flash_kernel<<<dim3(S_ / 16, NKV_, B_), 256, 0, stream>>>(qhib, qlob, khib, klob, vhib, vlob, attnb);
    gemm_bf16bt<<<dim3(H_ / BN, T_ / DBM), 256, 0, stream>>>(attnb, wot, hres, hidden, T_, H_, NH_ * HD_);
    rmsnorm_kernel<<<T_, 256, 0, stream>>>(hres, ln2, xnb, xn);
    router_kernel<<<T_ / 4, 256, 0, stream>>>(xn, rw, top_i, top_w);
    assign_kernel<<<1, 256, 0, stream>>>(top_i, top_w, tlist, pair_pos, counts, offsets);
    moe_gemm_gateup<<<dim3(I_ / BN, T_ / MBM, E_), 256, 0, stream>>>(xnb, wgt, wut, actb, tlist, counts, offsets);
    moe_gemm_down<<<dim3(H_ / BN, T_ / DBM, E_), 256, 0, stream>>>(actb, wdt, doutb, counts, offsets);
    combine_kernel<<<(T_ * H_) / 256, 256, 0, stream>>>(hres, doutb, pair_pos, top_w, out);
}

// Round 20
// 429.305 us; speedup vs baseline: 1.0289x; 1.0008x over previous
//
#include <hip/hip_runtime.h>
#include <hip/hip_bf16.h>
#include <math.h>

#define B_ 2
#define S_ 1024
#define H_ 1024
#define NH_ 16
#define NKV_ 4
#define HD_ 64
#define E_ 8
#define I_ 3584
#define T_ (B_*S_)

#define BM 64
#define BN 64
#define MBM 128   // gateup M-tile
#define DBM 64    // down / dense M-tile
#define MBK 64    // K-step

typedef __bf16 bf16x8 __attribute__((ext_vector_type(8)));
typedef float f32x4 __attribute__((ext_vector_type(4)));

__device__ __forceinline__ __bf16 bf_hi(float f) { return (__bf16)f; }
__device__ __forceinline__ __bf16 bf_lo(float f, __bf16 h) { return (__bf16)(f - (float)h); }

// XOR swizzle for [rows][64 bf16] tiles (128 B row stride).
__device__ __forceinline__ int swz128(int row, int col) {
    return (row * 128 + col * 2) ^ ((row & 7) << 4);
}

// ---------------- RoPE cos/sin table: tab[s][j] = (cos, sin)(s * 1e6^{-j/32}) ----------------
__global__ __launch_bounds__(256) void rope_table_kernel(float2* __restrict__ tab)
{
    int idx = blockIdx.x * 256 + threadIdx.x;
    if (idx >= S_ * 32) return;
    int s = idx >> 5, j = idx & 31;
    float inv = powf(1e6f, -(float)j / 32.0f);
    float ang = (float)s * inv;
    tab[idx] = make_float2(cosf(ang), sinf(ang));
}

// ---------------- fp32 -> (hi,lo) bf16 planes, optional scale ----------------
__global__ __launch_bounds__(256) void split_bf16_kernel(
    const float* __restrict__ src, __bf16* __restrict__ hi, __bf16* __restrict__ lo,
    float scale, int n8)
{
    int idx = blockIdx.x * 256 + threadIdx.x;
    if (idx >= n8) return;
    const float4* s = (const float4*)src + (size_t)idx * 2;
    float4 a = s[0], b = s[1];
    float f[8] = {a.x, a.y, a.z, a.w, b.x, b.y, b.z, b.w};
    bf16x8 vh, vl;
#pragma unroll
    for (int i = 0; i < 8; i++) {
        float x = f[i] * scale;
        __bf16 h = bf_hi(x);
        vh[i] = h;
        vl[i] = bf_lo(x, h);
    }
    ((bf16x8*)hi)[idx] = vh;
    ((bf16x8*)lo)[idx] = vl;
}

// ---------------- fp32 [M][N] -> bf16 transposed [N][M], per expert/z-slice ----------------
__global__ __launch_bounds__(256) void transpose_cvt_kernel(
    const float* __restrict__ src, __bf16* __restrict__ dst, int M, int N)
{
    int e = blockIdx.z;
    src += (size_t)e * M * N;
    dst += (size_t)e * M * N;
    int n0 = blockIdx.x * 64, m0 = blockIdx.y * 64;
    __shared__ __bf16 Ts[64][72];
    int tid = threadIdx.x;
#pragma unroll
    for (int i = 0; i < 16; i++) {
        int row = i * 4 + (tid >> 6);
        int col = tid & 63;
        Ts[row][col] = (__bf16)src[(size_t)(m0 + row) * N + n0 + col];
    }
    __syncthreads();
#pragma unroll
    for (int j = 0; j < 2; j++) {
        int n = (tid >> 3) + j * 32;
        int k8 = (tid & 7) * 8;
        bf16x8 v;
#pragma unroll
        for (int ii = 0; ii < 8; ii++) v[ii] = Ts[k8 + ii][n];
        *(bf16x8*)(dst + (size_t)(n0 + n) * M + m0 + k8) = v;
    }
}

// ---------------- RMSNorm: bf16 out (+ optional fp32 out) ----------------
__global__ __launch_bounds__(256) void rmsnorm_kernel(
    const float* __restrict__ x, const float* __restrict__ w,
    __bf16* __restrict__ outb, float* __restrict__ outf)
{
    int row = blockIdx.x;
    int tid = threadIdx.x;
    const float* xr = x + (size_t)row * H_;
    float vals[4];
    float ss = 0.f;
#pragma unroll
    for (int i = 0; i < 4; i++) {
        vals[i] = xr[tid + 256 * i];
        ss += vals[i] * vals[i];
    }
#pragma unroll
    for (int off = 32; off; off >>= 1) ss += __shfl_xor(ss, off);
    __shared__ float red[4];
    int wid = tid >> 6;
    if ((tid & 63) == 0) red[wid] = ss;
    __syncthreads();
    float tot = red[0] + red[1] + red[2] + red[3];
    float scale = rsqrtf(tot * (1.0f / H_) + 1e-5f);
#pragma unroll
    for (int i = 0; i < 4; i++) {
        float y = vals[i] * scale * w[tid + 256 * i];
        outb[(size_t)row * H_ + tid + 256 * i] = (__bf16)y;
        if (outf) outf[(size_t)row * H_ + tid + 256 * i] = y;
    }
}

// ---------------- Dense bf16 GEMM: A[M][K] bf16, BT[N][K] bf16 -> C[M][N] f32 (+res) ----
__global__ __launch_bounds__(256) void gemm_bf16bt(
    const __bf16* __restrict__ A, const __bf16* __restrict__ BT,
    float* __restrict__ C, const float* __restrict__ res,
    int M, int N, int Kd)
{
    int m0 = blockIdx.y * DBM;
    int n0 = blockIdx.x * BN;
    __shared__ __bf16 As[2][DBM * MBK];
    __shared__ __bf16 Bs[2][BN * MBK];
    int tid = threadIdx.x;
    int lane = tid & 63, wid = tid >> 6;
    f32x4 acc[4] = {};
    int ar = tid >> 2, ac = (tid & 3) * 16;
    int bn = tid >> 2, bc = (tid & 3) * 16;
    const __bf16* abase = A + (size_t)(m0 + ar) * Kd + ac;
    const __bf16* bbase = BT + (size_t)(n0 + bn) * Kd + bc;
    {
        char* Asb = (char*)As[0];
        char* Bsb = (char*)Bs[0];
#pragma unroll
        for (int g = 0; g < 2; g++) {
            *(bf16x8*)(Asb + swz128(ar, ac + g * 8)) = *(const bf16x8*)(abase + g * 8);
            *(bf16x8*)(Bsb + swz128(bn, bc + g * 8)) = *(const bf16x8*)(bbase + g * 8);
        }
    }
    bf16x8 pa[2], pb[2];
    if (Kd > MBK) {
#pragma unroll
        for (int g = 0; g < 2; g++) {
            pa[g] = *(const bf16x8*)(abase + MBK + g * 8);
            pb[g] = *(const bf16x8*)(bbase + MBK + g * 8);
        }
    }
    int cur = 0;
    int r = lane & 15, q8 = (lane >> 4) * 8;
    for (int kt = 0; kt < Kd; kt += MBK) {
        __syncthreads();
        char* Asb = (char*)As[cur];
        char* Bsb = (char*)Bs[cur];
#pragma unroll
        for (int kk = 0; kk < 2; kk++) {
            bf16x8 af = *(const bf16x8*)(Asb + swz128(wid * 16 + r, kk * 32 + q8));
            bf16x8 bfr[4];
#pragma unroll
            for (int n = 0; n < 4; n++)
                bfr[n] = *(const bf16x8*)(Bsb + swz128(n * 16 + r, kk * 32 + q8));
#pragma unroll
            for (int n = 0; n < 4; n++)
                acc[n] = __builtin_amdgcn_mfma_f32_16x16x32_bf16(af, bfr[n], acc[n], 0, 0, 0);
        }
        int kn = kt + MBK;
        if (kn < Kd) {
            char* Asw = (char*)As[cur ^ 1];
            char* Bsw = (char*)Bs[cur ^ 1];
#pragma unroll
            for (int g = 0; g < 2; g++) {
                *(bf16x8*)(Asw + swz128(ar, ac + g * 8)) = pa[g];
                *(bf16x8*)(Bsw + swz128(bn, bc + g * 8)) = pb[g];
            }
            int k2 = kn + MBK;
            if (k2 < Kd) {
#pragma unroll
                for (int g = 0; g < 2; g++) {
                    pa[g] = *(const bf16x8*)(abase + k2 + g * 8);
                    pb[g] = *(const bf16x8*)(bbase + k2 + g * 8);
                }
            }
            cur ^= 1;
        }
    }
    int cl = lane & 15, rb = (lane >> 4) * 4;
#pragma unroll
    for (int n = 0; n < 4; n++)
#pragma unroll
        for (int j = 0; j < 4; j++) {
            int row = m0 + wid * 16 + rb + j;
            int col = n0 + n * 16 + cl;
            size_t o = (size_t)row * N + col;
            float v = acc[n][j];
            if (res) v += res[o];
            C[o] = v;
        }
}

// ---------------- RoPE + hi/lo split (table-driven trig) ----------------
__global__ void rope_split_kernel(
    const float* __restrict__ x, const float2* __restrict__ tab,
    __bf16* __restrict__ hi, __bf16* __restrict__ lo,
    float scale, int heads, int total)
{
    int idx = blockIdx.x * blockDim.x + threadIdx.x;
    if (idx >= total) return;
    int j = idx & 31;
    int th = idx >> 5;
    int h = th % heads;
    int t = th / heads;
    int s = t & (S_ - 1);
    float2 cs = tab[s * 32 + j];
    float c = cs.x, sn = cs.y;
    size_t base = (size_t)t * heads * HD_ + (size_t)h * HD_;
    float x1 = x[base + j], x2 = x[base + 32 + j];
    float y1 = (x1 * c - x2 * sn) * scale;
    float y2 = (x2 * c + x1 * sn) * scale;
    __bf16 h1 = bf_hi(y1), h2 = bf_hi(y2);
    hi[base + j] = h1;       lo[base + j] = bf_lo(y1, h1);
    hi[base + 32 + j] = h2;  lo[base + 32 + j] = bf_lo(y2, h2);
}

// ---------------- MFMA flash attention — hi/lo planes, bf16 attn out ----------------
#define LP 72
__global__ __launch_bounds__(256) void flash_kernel(
    const __bf16* __restrict__ qhi, const __bf16* __restrict__ qlo_g,
    const __bf16* __restrict__ khi, const __bf16* __restrict__ klo,
    const __bf16* __restrict__ vhi, const __bf16* __restrict__ vlo,
    __bf16* __restrict__ o)
{
    __shared__ __bf16 Ks [64][LP];
    __shared__ __bf16 Ksl[64][LP];
    __shared__ __bf16 Vt [64][LP];
    __shared__ __bf16 Vtl[64][LP];
    __shared__ __bf16 Pl [4][16][LP];
    __shared__ __bf16 Pll[4][16][LP];

    int tid = threadIdx.x;
    int lane = tid & 63, wid = tid >> 6;
    int qr = lane & 15, quad = lane >> 4;
    int qt = (S_ / 16 - 1) - blockIdx.x;
    int kvh = blockIdx.y, b = blockIdx.z;
    int h = kvh * 4 + wid;
    int s0 = qt * 16;

    size_t qoff = ((size_t)(b * S_ + s0 + qr) * NH_ + h) * HD_ + quad * 8;
    bf16x8 qf[2], qlo[2];
#pragma unroll
    for (int ks = 0; ks < 2; ks++) {
        qf[ks]  = *(const bf16x8*)(qhi  + qoff + ks * 32);
        qlo[ks] = *(const bf16x8*)(qlo_g + qoff + ks * 32);
    }

    float m_run[4], l_run[4];
    f32x4 o_acc[4] = {};
#pragma unroll
    for (int j = 0; j < 4; j++) { m_run[j] = -1e30f; l_run[j] = 0.f; }

    int skey = tid >> 2, shd0 = (tid & 3) * 16;
    int vhd = tid & 63, vkey0 = (tid >> 6) * 16;

    for (int kt = 0; kt <= s0 + 15; kt += 64) {
        __syncthreads();
        {
            size_t koff = ((size_t)(b * S_ + kt + skey) * NKV_ + kvh) * HD_ + shd0;
            *(bf16x8*)&Ks [skey][shd0]     = *(const bf16x8*)(khi + koff);
            *(bf16x8*)&Ks [skey][shd0 + 8] = *(const bf16x8*)(khi + koff + 8);
            *(bf16x8*)&Ksl[skey][shd0]     = *(const bf16x8*)(klo + koff);
            *(bf16x8*)&Ksl[skey][shd0 + 8] = *(const bf16x8*)(klo + koff + 8);
        }
        {
            const __bf16* vh = vhi + ((size_t)(b * S_ + kt + vkey0) * NKV_ + kvh) * HD_ + vhd;
            const __bf16* vl = vlo + ((size_t)(b * S_ + kt + vkey0) * NKV_ + kvh) * HD_ + vhd;
            bf16x8 th0, th1, tl0, tl1;
#pragma unroll
            for (int i = 0; i < 8; i++) {
                th0[i] = vh[(size_t)i * (NKV_ * HD_)];
                th1[i] = vh[(size_t)(i + 8) * (NKV_ * HD_)];
                tl0[i] = vl[(size_t)i * (NKV_ * HD_)];
                tl1[i] = vl[(size_t)(i + 8) * (NKV_ * HD_)];
            }
            *(bf16x8*)&Vt [vhd][vkey0]     = th0;
            *(bf16x8*)&Vt [vhd][vkey0 + 8] = th1;
            *(bf16x8*)&Vtl[vhd][vkey0]     = tl0;
            *(bf16x8*)&Vtl[vhd][vkey0 + 8] = tl1;
        }
        __syncthreads();

        f32x4 sc4[4];
#pragma unroll
        for (int sub = 0; sub < 4; sub++) {
            int krow = sub * 16 + qr;
            bf16x8 kh0 = *(const bf16x8*)&Ks [krow][quad * 8];
            bf16x8 kh1 = *(const bf16x8*)&Ks [krow][32 + quad * 8];
            bf16x8 kl0 = *(const bf16x8*)&Ksl[krow][quad * 8];
            bf16x8 kl1 = *(const bf16x8*)&Ksl[krow][32 + quad * 8];
            f32x4 z = {};
            z = __builtin_amdgcn_mfma_f32_16x16x32_bf16(qf[0],  kh0, z, 0, 0, 0);
            z = __builtin_amdgcn_mfma_f32_16x16x32_bf16(qf[1],  kh1, z, 0, 0, 0);
            z = __builtin_amdgcn_mfma_f32_16x16x32_bf16(qlo[0], kh0, z, 0, 0, 0);
            z = __builtin_amdgcn_mfma_f32_16x16x32_bf16(qlo[1], kh1, z, 0, 0, 0);
            z = __builtin_amdgcn_mfma_f32_16x16x32_bf16(qf[0],  kl0, z, 0, 0, 0);
            z = __builtin_amdgcn_mfma_f32_16x16x32_bf16(qf[1],  kl1, z, 0, 0, 0);
            sc4[sub] = z;
        }
        if (kt + 63 > s0) {
#pragma unroll
            for (int sub = 0; sub < 4; sub++)
#pragma unroll
                for (int j = 0; j < 4; j++) {
                    int key = kt + sub * 16 + qr;
                    int row = s0 + quad * 4 + j;
                    if (key > row) sc4[sub][j] = -1e30f;
                }
        }
#pragma unroll
        for (int j = 0; j < 4; j++) {
            float mx = fmaxf(fmaxf(sc4[0][j], sc4[1][j]), fmaxf(sc4[2][j], sc4[3][j]));
#pragma unroll
            for (int off = 1; off < 16; off <<= 1) mx = fmaxf(mx, __shfl_xor(mx, off));
            float mn = fmaxf(m_run[j], mx);
            float scale = __expf(m_run[j] - mn);
            m_run[j] = mn;
            float rs = 0.f;
#pragma unroll
            for (int sub = 0; sub < 4; sub++) {
                float pe = __expf(sc4[sub][j] - mn);
                sc4[sub][j] = pe;
                rs += pe;
            }
#pragma unroll
            for (int off = 1; off < 16; off <<= 1) rs += __shfl_xor(rs, off);
            l_run[j] = l_run[j] * scale + rs;
#pragma unroll
            for (int sub = 0; sub < 4; sub++) o_acc[sub][j] *= scale;
        }
#pragma unroll
        for (int sub = 0; sub < 4; sub++)
#pragma unroll
            for (int j = 0; j < 4; j++) {
                float pe = sc4[sub][j];
                __bf16 hh = bf_hi(pe);
                Pl [wid][quad * 4 + j][sub * 16 + qr] = hh;
                Pll[wid][quad * 4 + j][sub * 16 + qr] = bf_lo(pe, hh);
            }
        __syncthreads();
        bf16x8 ph0 = *(const bf16x8*)&Pl [wid][qr][quad * 8];
        bf16x8 ph1 = *(const bf16x8*)&Pl [wid][qr][32 + quad * 8];
        bf16x8 pl0 = *(const bf16x8*)&Pll[wid][qr][quad * 8];
        bf16x8 pl1 = *(const bf16x8*)&Pll[wid][qr][32 + quad * 8];
#pragma unroll
        for (int sub = 0; sub < 4; sub++) {
            int vrow = sub * 16 + qr;
            bf16x8 vh0 = *(const bf16x8*)&Vt [vrow][quad * 8];
            bf16x8 vh1 = *(const bf16x8*)&Vt [vrow][32 + quad * 8];
            bf16x8 vl0 = *(const bf16x8*)&Vtl[vrow][quad * 8];
            bf16x8 vl1 = *(const bf16x8*)&Vtl[vrow][32 + quad * 8];
            o_acc[sub] = __builtin_amdgcn_mfma_f32_16x16x32_bf16(ph0, vh0, o_acc[sub], 0, 0, 0);
            o_acc[sub] = __builtin_amdgcn_mfma_f32_16x16x32_bf16(ph1, vh1, o_acc[sub], 0, 0, 0);
            o_acc[sub] = __builtin_amdgcn_mfma_f32_16x16x32_bf16(ph0, vl0, o_acc[sub], 0, 0, 0);
            o_acc[sub] = __builtin_amdgcn_mfma_f32_16x16x32_bf16(ph1, vl1, o_acc[sub], 0, 0, 0);
            o_acc[sub] = __builtin_amdgcn_mfma_f32_16x16x32_bf16(pl0, vh0, o_acc[sub], 0, 0, 0);
            o_acc[sub] = __builtin_amdgcn_mfma_f32_16x16x32_bf16(pl1, vh1, o_acc[sub], 0, 0, 0);
        }
    }
#pragma unroll
    for (int j = 0; j < 4; j++) {
        float inv = 1.f / l_run[j];
        int row = s0 + quad * 4 + j;
#pragma unroll
        for (int sub = 0; sub < 4; sub++)
            o[((size_t)(b * S_ + row) * NH_ + h) * HD_ + sub * 16 + qr] = (__bf16)(o_acc[sub][j] * inv);
    }
}

// ---------------- Router ----------------
__global__ __launch_bounds__(256) void router_kernel(
    const float* __restrict__ xn, const float* __restrict__ rw,
    int* __restrict__ top_i, float* __restrict__ top_w)
{
    int wid = threadIdx.x >> 6, lane = threadIdx.x & 63;
    int t = blockIdx.x * 4 + wid;
    const float* xr = xn + (size_t)t * H_;
    float acc[E_] = {};
    for (int c = 0; c < H_ / 64; c++) {
        float xd = xr[c * 64 + lane];
        const float* wrow = rw + (size_t)(c * 64 + lane) * E_;
#pragma unroll
        for (int e = 0; e < E_; e++) acc[e] += xd * wrow[e];
    }
#pragma unroll
    for (int e = 0; e < E_; e++) {
        float r = acc[e];
#pragma unroll
        for (int off = 32; off; off >>= 1) r += __shfl_xor(r, off);
        acc[e] = r;
    }
    if (lane == 0) {
        float mx = acc[0];
        for (int e = 1; e < E_; e++) mx = fmaxf(mx, acc[e]);
        float p[E_], sum = 0.f;
        for (int e = 0; e < E_; e++) { p[e] = __expf(acc[e] - mx); sum += p[e]; }
        float inv_s = 1.f / sum;
        for (int e = 0; e < E_; e++) p[e] *= inv_s;
        int i0 = 0;
        for (int e = 1; e < E_; e++) if (p[e] > p[i0]) i0 = e;
        int i1 = (i0 == 0) ? 1 : 0;
        for (int e = 0; e < E_; e++) if (e != i0 && p[e] > p[i1]) i1 = e;
        float v0 = p[i0], v1 = p[i1], inv = 1.f / (v0 + v1);
        top_i[t * 2] = i0; top_i[t * 2 + 1] = i1;
        top_w[t * 2] = v0 * inv; top_w[t * 2 + 1] = v1 * inv;
    }
}

// ---------------- Assignment ----------------
__global__ void assign_kernel(
    const int* __restrict__ top_i, const float* __restrict__ top_w,
    int* __restrict__ tlist, int* __restrict__ pair_pos,
    int* __restrict__ counts, int* __restrict__ offsets)
{
    __shared__ int cnt[E_], off[E_], fill[E_];
    int tid = threadIdx.x;
    if (tid < E_) { cnt[tid] = 0; fill[tid] = 0; }
    __syncthreads();
    for (int t = tid; t < T_; t += 256) {
        atomicAdd(&cnt[top_i[t * 2]], 1);
        atomicAdd(&cnt[top_i[t * 2 + 1]], 1);
    }
    __syncthreads();
    if (tid == 0) {
        int o = 0;
        for (int e = 0; e < E_; e++) { off[e] = o; o += cnt[e]; }
    }
    __syncthreads();
    for (int t = tid; t < T_; t += 256) {
        for (int j = 0; j < 2; j++) {
            int e = top_i[t * 2 + j];
            int pos = off[e] + atomicAdd(&fill[e], 1);
            tlist[pos] = t;
            pair_pos[t * 2 + j] = pos;
        }
    }
    __syncthreads();
    if (tid < E_) { counts[tid] = cnt[tid]; offsets[tid] = off[tid]; }
}

// ---------------- MoE gate+up GEMM: r12/r17 config (dbuf, 1 barrier/K-step) ----------------
__global__ __launch_bounds__(256) void moe_gemm_gateup(
    const __bf16* __restrict__ Xb, const __bf16* __restrict__ WgT, const __bf16* __restrict__ WuT,
    __bf16* __restrict__ act, const int* __restrict__ tlist,
    const int* __restrict__ counts, const int* __restrict__ offsets)
{
    int e = blockIdx.z;
    int cnt = counts[e], off = offsets[e];
    int m0 = blockIdx.y * MBM;
    if (m0 >= cnt) return;
    int n0 = blockIdx.x * BN;
    const __bf16* Bg = WgT + (size_t)e * H_ * I_;
    const __bf16* Bu = WuT + (size_t)e * H_ * I_;
    __shared__ __bf16 As[2][MBM * MBK];
    __shared__ __bf16 Gs[2][BN * MBK];
    __shared__ __bf16 Us[2][BN * MBK];
    __shared__ int rowidx[MBM];
    int tid = threadIdx.x;
    if (tid < MBM) {
        int rl = m0 + tid;
        rowidx[tid] = tlist[off + ((rl < cnt) ? rl : 0)];
    }
    __syncthreads();
    int lane = tid & 63, wid = tid >> 6;
    f32x4 accg[2][4] = {}, accu[2][4] = {};
    int ar = tid >> 1, ac = (tid & 1) * 32;
    int bn = tid >> 2, bc = (tid & 3) * 16;
    const __bf16* abase = Xb + (size_t)rowidx[ar] * H_ + ac;
    const __bf16* gbase = Bg + (size_t)(n0 + bn) * H_ + bc;
    const __bf16* ubase = Bu + (size_t)(n0 + bn) * H_ + bc;
    {
        char* Asb = (char*)As[0];
        char* Gsb = (char*)Gs[0];
        char* Usb = (char*)Us[0];
#pragma unroll
        for (int g = 0; g < 4; g++)
            *(bf16x8*)(Asb + swz128(ar, ac + g * 8)) = *(const bf16x8*)(abase + g * 8);
#pragma unroll
        for (int g = 0; g < 2; g++) {
            *(bf16x8*)(Gsb + swz128(bn, bc + g * 8)) = *(const bf16x8*)(gbase + g * 8);
            *(bf16x8*)(Usb + swz128(bn, bc + g * 8)) = *(const bf16x8*)(ubase + g * 8);
        }
    }
    bf16x8 pa[4], pg[2], pu[2];
    if (H_ > MBK) {
#pragma unroll
        for (int g = 0; g < 4; g++) pa[g] = *(const bf16x8*)(abase + MBK + g * 8);
#pragma unroll
        for (int g = 0; g < 2; g++) {
            pg[g] = *(const bf16x8*)(gbase + MBK + g * 8);
            pu[g] = *(const bf16x8*)(ubase + MBK + g * 8);
        }
    }
    int cur = 0;
    int r = lane & 15, q8 = (lane >> 4) * 8;
    for (int kt = 0; kt < H_; kt += MBK) {
        __syncthreads();
        char* Asb = (char*)As[cur];
        char* Gsb = (char*)Gs[cur];
        char* Usb = (char*)Us[cur];
#pragma unroll
        for (int kk = 0; kk < 2; kk++) {
            bf16x8 af[2], gf[4], uf[4];
#pragma unroll
            for (int m = 0; m < 2; m++)
                af[m] = *(const bf16x8*)(Asb + swz128(wid * 32 + m * 16 + r, kk * 32 + q8));
#pragma unroll
            for (int n = 0; n < 4; n++) {
                gf[n] = *(const bf16x8*)(Gsb + swz128(n * 16 + r, kk * 32 + q8));
                uf[n] = *(const bf16x8*)(Usb + swz128(n * 16 + r, kk * 32 + q8));
            }
#pragma unroll
            for (int m = 0; m < 2; m++)
#pragma unroll
                for (int n = 0; n < 4; n++) {
                    accg[m][n] = __builtin_amdgcn_mfma_f32_16x16x32_bf16(af[m], gf[n], accg[m][n], 0, 0, 0);
                    accu[m][n] = __builtin_amdgcn_mfma_f32_16x16x32_bf16(af[m], uf[n], accu[m][n], 0, 0, 0);
                }
        }
        int kn = kt + MBK;
        if (kn < H_) {
            char* Asw = (char*)As[cur ^ 1];
            char* Gsw = (char*)Gs[cur ^ 1];
            char* Usw = (char*)Us[cur ^ 1];
#pragma unroll
            for (int g = 0; g < 4; g++) *(bf16x8*)(Asw + swz128(ar, ac + g * 8)) = pa[g];
#pragma unroll
            for (int g = 0; g < 2; g++) {
                *(bf16x8*)(Gsw + swz128(bn, bc + g * 8)) = pg[g];
                *(bf16x8*)(Usw + swz128(bn, bc + g * 8)) = pu[g];
            }
            int k2 = kn + MBK;
            if (k2 < H_) {
#pragma unroll
                for (int g = 0; g < 4; g++) pa[g] = *(const bf16x8*)(abase + k2 + g * 8);
#pragma unroll
                for (int g = 0; g < 2; g++) {
                    pg[g] = *(const bf16x8*)(gbase + k2 + g * 8);
                    pu[g] = *(const bf16x8*)(ubase + k2 + g * 8);
                }
            }
            cur ^= 1;
        }
    }
    int cl = lane & 15, rb = (lane >> 4) * 4;
#pragma unroll
    for (int m = 0; m < 2; m++)
#pragma unroll
        for (int n = 0; n < 4; n++)
#pragma unroll
            for (int j = 0; j < 4; j++) {
                int rl = m0 + wid * 32 + m * 16 + rb + j;
                if (rl >= cnt) continue;
                int col = n0 + n * 16 + cl;
                float g = accg[m][n][j], u = accu[m][n][j];
                float sig = 1.f / (1.f + __expf(-g));
                act[(size_t)(off + rl) * I_ + col] = (__bf16)(g * sig * u);
            }
}

// ---------------- MoE down GEMM: r12/r17 config, bf16 dout ----------------
__global__ __launch_bounds__(256) void moe_gemm_down(
    const __bf16* __restrict__ act, const __bf16* __restrict__ WdT,
    __bf16* __restrict__ dout, const int* __restrict__ counts, const int* __restrict__ offsets)
{
    int e = blockIdx.z;
    int cnt = counts[e], off = offsets[e];
    int m0 = blockIdx.y * DBM;
    if (m0 >= cnt) return;
    int n0 = blockIdx.x * BN;
    const __bf16* Bw = WdT + (size_t)e * I_ * H_;
    __shared__ __bf16 As[2][DBM * MBK];
    __shared__ __bf16 Bs[2][BN * MBK];
    int tid = threadIdx.x;
    int lane = tid & 63, wid = tid >> 6;
    f32x4 acc[4] = {};
    int ar = tid >> 2, ac = (tid & 3) * 16;
    int bn = tid >> 2, bc = (tid & 3) * 16;
    int arow = m0 + ar; if (arow >= cnt) arow = cnt - 1;
    const __bf16* abase = act + (size_t)(off + arow) * I_ + ac;
    const __bf16* bbase = Bw + (size_t)(n0 + bn) * I_ + bc;
    {
        char* Asb = (char*)As[0];
        char* Bsb = (char*)Bs[0];
#pragma unroll
        for (int g = 0; g < 2; g++) {
            *(bf16x8*)(Asb + swz128(ar, ac + g * 8)) = *(const bf16x8*)(abase + g * 8);
            *(bf16x8*)(Bsb + swz128(bn, bc + g * 8)) = *(const bf16x8*)(bbase + g * 8);
        }
    }
    bf16x8 pa[2], pb[2];
    if (I_ > MBK) {
#pragma unroll
        for (int g = 0; g < 2; g++) {
            pa[g] = *(const bf16x8*)(abase + MBK + g * 8);
            pb[g] = *(const bf16x8*)(bbase + MBK + g * 8);
        }
    }
    int cur = 0;
    int r = lane & 15, q8 = (lane >> 4) * 8;
    for (int kt = 0; kt < I_; kt += MBK) {
        __syncthreads();
        char* Asb = (char*)As[cur];
        char* Bsb = (char*)Bs[cur];
#pragma unroll
        for (int kk = 0; kk < 2; kk++) {
            bf16x8 af = *(const bf16x8*)(Asb + swz128(wid * 16 + r, kk * 32 + q8));
            bf16x8 bfr[4];
#pragma unroll
            for (int n = 0; n < 4; n++)
                bfr[n] = *(const bf16x8*)(Bsb + swz128(n * 16 + r, kk * 32 + q8));
#pragma unroll
            for (int n = 0; n < 4; n++)
                acc[n] = __builtin_amdgcn_mfma_f32_16x16x32_bf16(af, bfr[n], acc[n], 0, 0, 0);
        }
        int kn = kt + MBK;
        if (kn < I_) {
            char* Asw = (char*)As[cur ^ 1];
            char* Bsw = (char*)Bs[cur ^ 1];
#pragma unroll
            for (int g = 0; g < 2; g++) {
                *(bf16x8*)(Asw + swz128(ar, ac + g * 8)) = pa[g];
                *(bf16x8*)(Bsw + swz128(bn, bc + g * 8)) = pb[g];
            }
            int k2 = kn + MBK;
            if (k2 < I_) {
#pragma unroll
                for (int g = 0; g < 2; g++) {
                    pa[g] = *(const bf16x8*)(abase + k2 + g * 8);
                    pb[g] = *(const bf16x8*)(bbase + k2 + g * 8);
                }
            }
            cur ^= 1;
        }
    }
    int cl = lane & 15, rb = (lane >> 4) * 4;
#pragma unroll
    for (int n = 0; n < 4; n++)
#pragma unroll
        for (int j = 0; j < 4; j++) {
            int rl = m0 + wid * 16 + rb + j;
            if (rl >= cnt) continue;
            int col = n0 + n * 16 + cl;
            dout[(size_t)(off + rl) * H_ + col] = (__bf16)acc[n][j];
        }
}

// ---------------- Final combine (vectorized: 8 elems/thread) ----------------
__global__ __launch_bounds__(256) void combine_kernel(
    const float* __restrict__ hres, const __bf16* __restrict__ dout,
    const int* __restrict__ pair_pos, const float* __restrict__ top_w,
    float* __restrict__ out)
{
    int idx = blockIdx.x * 256 + threadIdx.x;   // one per 8 elements
    int t = idx >> 7, d8 = (idx & 127) * 8;
    int p0 = pair_pos[t * 2], p1 = pair_pos[t * 2 + 1];
    float w0 = top_w[t * 2], w1 = top_w[t * 2 + 1];
    const float4* h4 = (const float4*)(hres + (size_t)t * H_ + d8);
    bf16x8 dv0 = *(const bf16x8*)(dout + (size_t)p0 * H_ + d8);
    bf16x8 dv1 = *(const bf16x8*)(dout + (size_t)p1 * H_ + d8);
    float4 o0 = h4[0], o1 = h4[1];
    float r[8];
#pragma unroll
    for (int i = 0; i < 8; i++) r[i] = w0 * (float)dv0[i] + w1 * (float)dv1[i];
    o0.x += r[0]; o0.y += r[1]; o0.z += r[2]; o0.w += r[3];
    o1.x += r[4]; o1.y += r[5]; o1.z += r[6]; o1.w += r[7];
    float4* ov = (float4*)(out + (size_t)t * H_ + d8);
    ov[0] = o0; ov[1] = o1;
}

extern "C" void kernel_launch(void* const* d_in, const int* in_sizes, int n_in,
                              void* d_out, int out_size, void* d_ws, size_t ws_size,
                              hipStream_t stream) {
    const float* hidden = (const float*)d_in[0];
    const float* ln1 = (const float*)d_in[1];
    const float* wq = (const float*)d_in[2];
    const float* wk = (const float*)d_in[3];
    const float* wv = (const float*)d_in[4];
    const float* wo = (const float*)d_in[5];
    const float* ln2 = (const float*)d_in[6];
    const float* rw = (const float*)d_in[7];
    const float* wg = (const float*)d_in[8];
    const float* wu = (const float*)d_in[9];
    const float* wd = (const float*)d_in[10];
    float* out = (float*)d_out;

    char* ws = (char*)d_ws;
    size_t o = 0;
    auto alloc = [&](size_t bytes) -> void* {
        void* p = ws + o;
        o += (bytes + 255) & ~(size_t)255;
        return p;
    };
    float* xn   = (float*)alloc((size_t)T_ * H_ * 4);
    float* qb   = (float*)alloc((size_t)T_ * NH_ * HD_ * 4);
    float* kb   = (float*)alloc((size_t)T_ * NKV_ * HD_ * 4);
    float* vb   = (float*)alloc((size_t)T_ * NKV_ * HD_ * 4);
    float* hres = (float*)alloc((size_t)T_ * H_ * 4);
    int*   top_i    = (int*)alloc((size_t)T_ * 2 * 4);
    float* top_w    = (float*)alloc((size_t)T_ * 2 * 4);
    int*   pair_pos = (int*)alloc((size_t)T_ * 2 * 4);
    int*   tlist    = (int*)alloc((size_t)T_ * 2 * 4);
    int*   counts   = (int*)alloc(E_ * 4);
    int*   offsets  = (int*)alloc(E_ * 4);
    __bf16* actb  = (__bf16*)alloc((size_t)T_ * 2 * I_ * 2);
    __bf16* doutb = (__bf16*)alloc((size_t)T_ * 2 * H_ * 2);
    __bf16* xnb1 = (__bf16*)alloc((size_t)T_ * H_ * 2);
    __bf16* xnb  = (__bf16*)alloc((size_t)T_ * H_ * 2);
    __bf16* attnb = (__bf16*)alloc((size_t)T_ * H_ * 2);
    __bf16* wgt = (__bf16*)alloc((size_t)E_ * H_ * I_ * 2);
    __bf16* wut = (__bf16*)alloc((size_t)E_ * H_ * I_ * 2);
    __bf16* wdt = (__bf16*)alloc((size_t)E_ * I_ * H_ * 2);
    __bf16* wqt = (__bf16*)alloc((size_t)H_ * NH_ * HD_ * 2);
    __bf16* wkt = (__bf16*)alloc((size_t)H_ * NKV_ * HD_ * 2);
    __bf16* wvt = (__bf16*)alloc((size_t)H_ * NKV_ * HD_ * 2);
    __bf16* wot = (__bf16*)alloc((size_t)NH_ * HD_ * H_ * 2);
    __bf16* qhib = (__bf16*)alloc((size_t)T_ * NH_ * HD_ * 2);
    __bf16* qlob = (__bf16*)alloc((size_t)T_ * NH_ * HD_ * 2);
    __bf16* khib = (__bf16*)alloc((size_t)T_ * NKV_ * HD_ * 2);
    __bf16* klob = (__bf16*)alloc((size_t)T_ * NKV_ * HD_ * 2);
    __bf16* vhib = (__bf16*)alloc((size_t)T_ * NKV_ * HD_ * 2);
    __bf16* vlob = (__bf16*)alloc((size_t)T_ * NKV_ * HD_ * 2);
    float2* ctab = (float2*)alloc((size_t)S_ * 32 * 8);

    rope_table_kernel<<<(S_ * 32 + 255) / 256, 256, 0, stream>>>(ctab);
    transpose_cvt_kernel<<<dim3(I_ / 64, H_ / 64, E_), 256, 0, stream>>>(wg, wgt, H_, I_);
    transpose_cvt_kernel<<<dim3(I_ / 64, H_ / 64, E_), 256, 0, stream>>>(wu, wut, H_, I_);
    transpose_cvt_kernel<<<dim3(H_ / 64, I_ / 64, E_), 256, 0, stream>>>(wd, wdt, I_, H_);
    transpose_cvt_kernel<<<dim3((NH_ * HD_) / 64, H_ / 64, 1), 256, 0, stream>>>(wq, wqt, H_, NH_ * HD_);
    transpose_cvt_kernel<<<dim3((NKV_ * HD_) / 64, H_ / 64, 1), 256, 0, stream>>>(wk, wkt, H_, NKV_ * HD_);
    transpose_cvt_kernel<<<dim3((NKV_ * HD_) / 64, H_ / 64, 1), 256, 0, stream>>>(wv, wvt, H_, NKV_ * HD_);
    transpose_cvt_kernel<<<dim3(H_ / 64, (NH_ * HD_) / 64, 1), 256, 0, stream>>>(wo, wot, NH_ * HD_, H_);

    rmsnorm_kernel<<<T_, 256, 0, stream>>>(hidden, ln1, xnb1, nullptr);
    gemm_bf16bt<<<dim3((NH_ * HD_) / BN, T_ / DBM), 256, 0, stream>>>(xnb1, wqt, qb, nullptr, T_, NH_ * HD_, H_);
    gemm_bf16bt<<<dim3((NKV_ * HD_) / BN, T_ / DBM), 256, 0, stream>>>(xnb1, wkt, kb, nullptr, T_, NKV_ * HD_, H_);
    gemm_bf16bt<<<dim3((NKV_ * HD_) / BN, T_ / DBM), 256, 0, stream>>>(xnb1, wvt, vb, nullptr, T_, NKV_ * HD_, H_);
    {
        int tq = T_ * NH_ * 32, tk = T_ * NKV_ * 32;
        rope_split_kernel<<<(tq + 255) / 256, 256, 0, stream>>>(qb, ctab, qhib, qlob, 0.125f, NH_, tq);
        rope_split_kernel<<<(tk + 255) / 256, 256, 0, stream>>>(kb, ctab, khib, klob, 1.0f, NKV_, tk);
        int nk8 = T_ * NKV_ * HD_ / 8;
        split_bf16_kernel<<<(nk8 + 255) / 256, 256, 0, stream>>>(vb, vhib, vlob, 1.0f, nk8);
    }
    flash_kernel<<<dim3(S_ / 16, NKV_, B_), 256, 0, stream>>>(qhib, qlob, khib, klob, vhib, vlob, attnb);
    gemm_bf16bt<<<dim3(H_ / BN, T_ / DBM), 256, 0, stream>>>(attnb, wot, hres, hidden, T_, H_, NH_ * HD_);
    rmsnorm_kernel<<<T_, 256, 0, stream>>>(hres, ln2, xnb, xn);
    router_kernel<<<T_ / 4, 256, 0, stream>>>(xn, rw, top_i, top_w);
    assign_kernel<<<1, 256, 0, stream>>>(top_i, top_w, tlist, pair_pos, counts, offsets);
    moe_gemm_gateup<<<dim3(I_ / BN, T_ / MBM, E_), 256, 0, stream>>>(xnb, wgt, wut, actb, tlist, counts, offsets);
    moe_gemm_down<<<dim3(H_ / BN, T_ / DBM, E_), 256, 0, stream>>>(actb, wdt, doutb, counts, offsets);
    combine_kernel<<<(T_ * H_) / 8 / 256, 256, 0, stream>>>(hres, doutb, pair_pos, top_w, out);
}